// Round 1
// baseline (1986.245 us; speedup 1.0000x reference)
//
#include <hip/hip_runtime.h>
#include <math.h>

#define NSLOPE 0.2f

__device__ __forceinline__ float elu1(float x) { return x > 0.f ? x : expm1f(x); }

// ---------------- l2-normalize rows of x [N,100] -> xn ----------------
__global__ void k_l2norm_x(const float* __restrict__ x, float* __restrict__ xn, int N) {
  int wid  = (int)((blockIdx.x * (unsigned)blockDim.x + threadIdx.x) >> 6);
  int lane = threadIdx.x & 63;
  if (wid >= N) return;
  const float* p = x + (size_t)wid * 100;
  float v0 = p[lane];
  float v1 = (lane < 36) ? p[lane + 64] : 0.f;
  float ss = v0 * v0 + v1 * v1;
#pragma unroll
  for (int m = 1; m < 64; m <<= 1) ss += __shfl_xor(ss, m, 64);
  float inv = 1.f / fmaxf(sqrtf(ss), 1e-12f);
  float* o = xn + (size_t)wid * 100;
  o[lane] = v0 * inv;
  if (lane < 36) o[lane + 64] = v1 * inv;
}

// ---------------- C[R,200] = A[R,K](lda) @ W[:, c0:c0+K].T (+ bias) ----------------
// block 256: 32-row x 64-col tile; grid (4, ceil(R/32))
__global__ void k_gemm(const float* __restrict__ A, int lda,
                       const float* __restrict__ W, int ldw, int c0,
                       const float* __restrict__ bias,
                       float* __restrict__ C, int R, int K) {
  __shared__ float As[32][200];
  int row0 = blockIdx.y * 32;
  int t = threadIdx.x;
  int r = t >> 3;
  for (int k = (t & 7); k < K; k += 8) {
    int rr = row0 + r;
    As[r][k] = (rr < R) ? A[(size_t)rr * lda + k] : 0.f;
  }
  __syncthreads();
  int c = blockIdx.x * 64 + (t & 63);
  int rb = (t >> 6) << 3;
  if (c >= 200) return;
  const float* Wr = W + (size_t)c * ldw + c0;
  float acc[8] = {0.f, 0.f, 0.f, 0.f, 0.f, 0.f, 0.f, 0.f};
  for (int k = 0; k < K; ++k) {
    float w = Wr[k];
#pragma unroll
    for (int i = 0; i < 8; ++i) acc[i] += As[rb + i][k] * w;
  }
  float bv = bias ? bias[c] : 0.f;
#pragma unroll
  for (int i = 0; i < 8; ++i) {
    int rr = row0 + rb + i;
    if (rr < R) C[(size_t)rr * 200 + c] = acc[i] + bv;
  }
}

// ---------------- q[n,h] = sum_k avec[h*100+k] * P[n*200+h*100+k] ----------------
__global__ void k_attdot(const float* __restrict__ P, const float* __restrict__ avec,
                         float* __restrict__ q, int R) {
  int i = blockIdx.x * blockDim.x + threadIdx.x;
  if (i >= R * 2) return;
  int n = i >> 1, h = i & 1;
  const float* p = P + (size_t)n * 200 + h * 100;
  const float* a = avec + h * 100;
  float s = 0.f;
#pragma unroll 4
  for (int k = 0; k < 100; ++k) s += p[k] * a[k];
  q[i] = s;
}

// ---------------- per-edge logits + denominators ----------------
__global__ void k_edge_logits(const int* __restrict__ row, const int* __restrict__ col,
                              const int* __restrict__ ety,
                              const float* __restrict__ qA, const float* __restrict__ qB,
                              const float* __restrict__ q3i,
                              const float* __restrict__ qC, const float* __restrict__ qD,
                              const float* __restrict__ q3o,
                              float* __restrict__ eIn, float* __restrict__ eOut,
                              float* __restrict__ dIn, float* __restrict__ dOut, int E) {
  int e = blockIdx.x * blockDim.x + threadIdx.x;
  if (e >= E) return;
  int r = row[e], c = col[e], tt = ety[e];
#pragma unroll
  for (int h = 0; h < 2; ++h) {
    float a = qA[r * 2 + h] + qB[c * 2 + h] + q3i[tt * 2 + h];
    float la = a > 0.f ? a : NSLOPE * a;
    float ea = expf(-la);
    eIn[e * 2 + h] = ea;
    atomicAdd(&dIn[c * 2 + h], ea);
    float b = qC[r * 2 + h] + qD[c * 2 + h] + q3o[tt * 2 + h];
    float lb = b > 0.f ? b : NSLOPE * b;
    float eb = expf(-lb);
    eOut[e * 2 + h] = eb;
    atomicAdd(&dOut[r * 2 + h], eb);
  }
}

// ---------------- per-edge weighted scatter (wave per edge) ----------------
// in : PB[col] += win * (PA[row] + P3i[t])
// out: PC[row] += wout * (PD[col] + P3o[t])
__global__ void k_edge_accum(const int* __restrict__ row, const int* __restrict__ col,
                             const int* __restrict__ ety,
                             const float* __restrict__ eIn, const float* __restrict__ eOut,
                             const float* __restrict__ dIn, const float* __restrict__ dOut,
                             const float* __restrict__ PA, const float* __restrict__ P3i,
                             const float* __restrict__ PD, const float* __restrict__ P3o,
                             float* __restrict__ PB, float* __restrict__ PC, int E) {
  int wid  = (int)((blockIdx.x * (unsigned)blockDim.x + threadIdx.x) >> 6);
  int lane = threadIdx.x & 63;
  if (wid >= E || lane >= 50) return;
  int e = wid;
  int r = row[e], c = col[e], tt = ety[e];
  int h = lane < 25 ? 0 : 1;
  int j = lane * 4;
  float win  = eIn[e * 2 + h] / dIn[c * 2 + h];
  float wout = eOut[e * 2 + h] / dOut[r * 2 + h];
  const float4 pa = *(const float4*)(PA  + (size_t)r  * 200 + j);
  const float4 p3 = *(const float4*)(P3i + (size_t)tt * 200 + j);
  const float4 pd = *(const float4*)(PD  + (size_t)c  * 200 + j);
  const float4 p4 = *(const float4*)(P3o + (size_t)tt * 200 + j);
  float* pb = PB + (size_t)c * 200 + j;
  float* pc = PC + (size_t)r * 200 + j;
  atomicAdd(pb + 0, win * (pa.x + p3.x));
  atomicAdd(pb + 1, win * (pa.y + p3.y));
  atomicAdd(pb + 2, win * (pa.z + p3.z));
  atomicAdd(pb + 3, win * (pa.w + p3.w));
  atomicAdd(pc + 0, wout * (pd.x + p4.x));
  atomicAdd(pc + 1, wout * (pd.y + p4.y));
  atomicAdd(pc + 2, wout * (pd.z + p4.z));
  atomicAdd(pc + 3, wout * (pd.w + p4.w));
}

// ---------------- gate + elu + per-head l2 (wave per node) ----------------
// hin = elu(PB[n]) (0 if no in-edge); hout = elu(PC[n]) (0 if no out-edge)
// al = sigmoid(Wg[0:100].hin_h + Wg[100:200].hout_h + bg); he = elu(mix); l2-normalize per head
__global__ void k_gate_norm(const float* __restrict__ PB, const float* __restrict__ PC,
                            const float* __restrict__ dIn, const float* __restrict__ dOut,
                            const float* __restrict__ Wg, const float* __restrict__ bg,
                            float* __restrict__ H, int N) {
  int wid  = (int)((blockIdx.x * (unsigned)blockDim.x + threadIdx.x) >> 6);
  int lane = threadIdx.x & 63;
  if (wid >= N) return;
  int n = wid;
  int half = lane >> 5, i = lane & 31;
  bool act = i < 25;
  int j = half * 100 + i * 4;
  float4 hin = {0.f, 0.f, 0.f, 0.f}, hout = {0.f, 0.f, 0.f, 0.f};
  float gp = 0.f;
  if (act) {
    if (dIn[n * 2 + half] != 0.f) {
      float4 v = *(const float4*)(PB + (size_t)n * 200 + j);
      hin.x = elu1(v.x); hin.y = elu1(v.y); hin.z = elu1(v.z); hin.w = elu1(v.w);
    }
    if (dOut[n * 2 + half] != 0.f) {
      float4 v = *(const float4*)(PC + (size_t)n * 200 + j);
      hout.x = elu1(v.x); hout.y = elu1(v.y); hout.z = elu1(v.z); hout.w = elu1(v.w);
    }
    int k = i * 4;
    gp = Wg[k] * hin.x + Wg[k + 1] * hin.y + Wg[k + 2] * hin.z + Wg[k + 3] * hin.w +
         Wg[100 + k] * hout.x + Wg[100 + k + 1] * hout.y +
         Wg[100 + k + 2] * hout.z + Wg[100 + k + 3] * hout.w;
  }
#pragma unroll
  for (int m = 1; m < 32; m <<= 1) gp += __shfl_xor(gp, m, 32);
  float al = 1.f / (1.f + expf(-(gp + bg[0])));
  float4 he;
  he.x = elu1(al * hin.x + (1.f - al) * hout.x);
  he.y = elu1(al * hin.y + (1.f - al) * hout.y);
  he.z = elu1(al * hin.z + (1.f - al) * hout.z);
  he.w = elu1(al * hin.w + (1.f - al) * hout.w);
  float ss = he.x * he.x + he.y * he.y + he.z * he.z + he.w * he.w;
#pragma unroll
  for (int m = 1; m < 32; m <<= 1) ss += __shfl_xor(ss, m, 32);
  float inv = 1.f / fmaxf(sqrtf(ss), 1e-12f);
  if (act) {
    float4 o; o.x = he.x * inv; o.y = he.y * inv; o.z = he.z * inv; o.w = he.w * inv;
    *(float4*)(H + (size_t)n * 200 + j) = o;
  }
}

// ---------------- final: out = l2_perhead(hent + h2) ----------------
__global__ void k_final_norm(const float* __restrict__ hent, const float* __restrict__ h2,
                             float* __restrict__ out, int N) {
  int wid  = (int)((blockIdx.x * (unsigned)blockDim.x + threadIdx.x) >> 6);
  int lane = threadIdx.x & 63;
  if (wid >= N) return;
  int n = wid;
  int half = lane >> 5, i = lane & 31;
  bool act = i < 25;
  int j = half * 100 + i * 4;
  float4 v = {0.f, 0.f, 0.f, 0.f};
  if (act) {
    float4 a = *(const float4*)(hent + (size_t)n * 200 + j);
    float4 b = *(const float4*)(h2 + (size_t)n * 200 + j);
    v.x = a.x + b.x; v.y = a.y + b.y; v.z = a.z + b.z; v.w = a.w + b.w;
  }
  float ss = v.x * v.x + v.y * v.y + v.z * v.z + v.w * v.w;
#pragma unroll
  for (int m = 1; m < 32; m <<= 1) ss += __shfl_xor(ss, m, 32);
  float inv = 1.f / fmaxf(sqrtf(ss), 1e-12f);
  if (act) {
    float4 o; o.x = v.x * inv; o.y = v.y * inv; o.z = v.z * inv; o.w = v.w * inv;
    *(float4*)(out + (size_t)n * 200 + j) = o;
  }
}

extern "C" void kernel_launch(void* const* d_in, const int* in_sizes, int n_in,
                              void* d_out, int out_size, void* d_ws, size_t ws_size,
                              hipStream_t stream) {
  const float* x    = (const float*)d_in[0];
  const float* g    = (const float*)d_in[1];
  const float* W1in = (const float*)d_in[2];
  const float* b1in = (const float*)d_in[3];
  const float* a1in = (const float*)d_in[4];
  const float* W1out= (const float*)d_in[5];
  const float* b1out= (const float*)d_in[6];
  const float* a1out= (const float*)d_in[7];
  const float* Wa1  = (const float*)d_in[8];
  const float* ba1  = (const float*)d_in[9];
  const float* W2in = (const float*)d_in[10];
  const float* b2in = (const float*)d_in[11];
  const float* a2in = (const float*)d_in[12];
  const float* W2out= (const float*)d_in[13];
  const float* b2out= (const float*)d_in[14];
  const float* a2out= (const float*)d_in[15];
  const float* Wa2  = (const float*)d_in[16];
  const float* ba2  = (const float*)d_in[17];
  const float* Went = (const float*)d_in[18];
  const float* bent = (const float*)d_in[19];
  const float* Wrel = (const float*)d_in[20];
  const float* brel = (const float*)d_in[21];
  const int*  eidx  = (const int*)d_in[22];
  const int*  ety   = (const int*)d_in[23];

  const int N = in_sizes[0] / 100;
  const int M = in_sizes[1] / 100;
  const int E = in_sizes[23];
  const int* row = eidx;
  const int* col = eidx + E;
  float* out = (float*)d_out;

  float* ws = (float*)d_ws;
  size_t off = 0;
  auto alloc = [&](size_t nf) { float* p = ws + off; off += (nf + 3) & ~(size_t)3; return p; };
  float* xn  = alloc((size_t)N * 100);
  float* PA  = alloc((size_t)N * 200);
  float* PB  = alloc((size_t)N * 200);
  float* PC  = alloc((size_t)N * 200);
  float* PD  = alloc((size_t)N * 200);
  float* P3i = alloc((size_t)M * 200);
  float* P3o = alloc((size_t)M * 200);
  float* qA  = alloc((size_t)N * 2);
  float* qB  = alloc((size_t)N * 2);
  float* qC  = alloc((size_t)N * 2);
  float* qD  = alloc((size_t)N * 2);
  float* q3i = alloc((size_t)M * 2);
  float* q3o = alloc((size_t)M * 2);
  float* eI  = alloc((size_t)E * 2);
  float* eO  = alloc((size_t)E * 2);
  float* dI  = alloc((size_t)N * 2);
  float* dO  = alloc((size_t)N * 2);
  float* h1  = alloc((size_t)N * 200);
  float* h2  = alloc((size_t)N * 200);

  dim3 gg(4, (N + 31) / 32);
  dim3 gm(4, (M + 31) / 32);
  int gN4 = (N + 3) / 4;   // wave-per-node blocks
  int gE4 = (E + 3) / 4;   // wave-per-edge blocks
  int gE  = (E + 255) / 256;
  int adN = (N * 2 + 255) / 256;
  int adM = (M * 2 + 255) / 256;

  k_l2norm_x<<<gN4, 256, 0, stream>>>(x, xn, N);

  // ---------- layer 1 ----------
  k_gemm<<<gg, 256, 0, stream>>>(xn, 100, W1in, 300, 0, nullptr, PA, N, 100);
  k_gemm<<<gg, 256, 0, stream>>>(xn, 100, W1in, 300, 100, nullptr, PB, N, 100);
  k_gemm<<<gg, 256, 0, stream>>>(xn, 100, W1out, 300, 0, nullptr, PC, N, 100);
  k_gemm<<<gg, 256, 0, stream>>>(xn, 100, W1out, 300, 100, nullptr, PD, N, 100);
  k_gemm<<<gm, 256, 0, stream>>>(g, 100, W1in, 300, 200, b1in, P3i, M, 100);
  k_gemm<<<gm, 256, 0, stream>>>(g, 100, W1out, 300, 200, b1out, P3o, M, 100);

  k_attdot<<<adN, 256, 0, stream>>>(PA, a1in, qA, N);
  k_attdot<<<adN, 256, 0, stream>>>(PB, a1in, qB, N);
  k_attdot<<<adN, 256, 0, stream>>>(PC, a1out, qC, N);
  k_attdot<<<adN, 256, 0, stream>>>(PD, a1out, qD, N);
  k_attdot<<<adM, 256, 0, stream>>>(P3i, a1in, q3i, M);
  k_attdot<<<adM, 256, 0, stream>>>(P3o, a1out, q3o, M);

  hipMemsetAsync(dI, 0, (size_t)N * 2 * sizeof(float), stream);
  hipMemsetAsync(dO, 0, (size_t)N * 2 * sizeof(float), stream);
  k_edge_logits<<<gE, 256, 0, stream>>>(row, col, ety, qA, qB, q3i, qC, qD, q3o,
                                        eI, eO, dI, dO, E);
  k_edge_accum<<<gE4, 256, 0, stream>>>(row, col, ety, eI, eO, dI, dO,
                                        PA, P3i, PD, P3o, PB, PC, E);
  k_gate_norm<<<gN4, 256, 0, stream>>>(PB, PC, dI, dO, Wa1, ba1, h1, N);

  // ---------- layer 2 ----------
  k_gemm<<<gg, 256, 0, stream>>>(h1, 200, W2in, 500, 0, nullptr, PA, N, 200);
  k_gemm<<<gg, 256, 0, stream>>>(h1, 200, W2in, 500, 200, nullptr, PB, N, 200);
  k_gemm<<<gg, 256, 0, stream>>>(h1, 200, W2out, 500, 0, nullptr, PC, N, 200);
  k_gemm<<<gg, 256, 0, stream>>>(h1, 200, W2out, 500, 200, nullptr, PD, N, 200);
  k_gemm<<<gm, 256, 0, stream>>>(g, 100, W2in, 500, 400, b2in, P3i, M, 100);
  k_gemm<<<gm, 256, 0, stream>>>(g, 100, W2out, 500, 400, b2out, P3o, M, 100);

  k_attdot<<<adN, 256, 0, stream>>>(PA, a2in, qA, N);
  k_attdot<<<adN, 256, 0, stream>>>(PB, a2in, qB, N);
  k_attdot<<<adN, 256, 0, stream>>>(PC, a2out, qC, N);
  k_attdot<<<adN, 256, 0, stream>>>(PD, a2out, qD, N);
  k_attdot<<<adM, 256, 0, stream>>>(P3i, a2in, q3i, M);
  k_attdot<<<adM, 256, 0, stream>>>(P3o, a2out, q3o, M);

  hipMemsetAsync(dI, 0, (size_t)N * 2 * sizeof(float), stream);
  hipMemsetAsync(dO, 0, (size_t)N * 2 * sizeof(float), stream);
  k_edge_logits<<<gE, 256, 0, stream>>>(row, col, ety, qA, qB, q3i, qC, qD, q3o,
                                        eI, eO, dI, dO, E);
  k_edge_accum<<<gE4, 256, 0, stream>>>(row, col, ety, eI, eO, dI, dO,
                                        PA, P3i, PD, P3o, PB, PC, E);
  k_gate_norm<<<gN4, 256, 0, stream>>>(PB, PC, dI, dO, Wa2, ba2, h2, N);

  // ---------- final ----------
  k_gemm<<<gg, 256, 0, stream>>>(xn, 100, Went, 100, 0, bent, PA, N, 100);
  k_final_norm<<<gN4, 256, 0, stream>>>(PA, h2, out, N);
  k_gemm<<<gm, 256, 0, stream>>>(g, 100, Wrel, 100, 0, brel, out + (size_t)N * 200, M, 100);
}

// Round 2
// 651.178 us; speedup vs baseline: 3.0502x; 3.0502x over previous
//
#include <hip/hip_runtime.h>
#include <math.h>

#define NSLOPE 0.2f

__device__ __forceinline__ float elu1(float x) { return x > 0.f ? x : expm1f(x); }

// ---------------- l2-normalize rows of x [N,100] -> xn ----------------
__global__ void k_l2norm_x(const float* __restrict__ x, float* __restrict__ xn, int N) {
  int wid  = (int)((blockIdx.x * (unsigned)blockDim.x + threadIdx.x) >> 6);
  int lane = threadIdx.x & 63;
  if (wid >= N) return;
  const float* p = x + (size_t)wid * 100;
  float v0 = p[lane];
  float v1 = (lane < 36) ? p[lane + 64] : 0.f;
  float ss = v0 * v0 + v1 * v1;
#pragma unroll
  for (int m = 1; m < 64; m <<= 1) ss += __shfl_xor(ss, m, 64);
  float inv = 1.f / fmaxf(sqrtf(ss), 1e-12f);
  float* o = xn + (size_t)wid * 100;
  o[lane] = v0 * inv;
  if (lane < 36) o[lane + 64] = v1 * inv;
}

// ---------------- C[R,200] = A[R,K](lda) @ W[:, c0:c0+K].T (+ bias) ----------------
__global__ void k_gemm(const float* __restrict__ A, int lda,
                       const float* __restrict__ W, int ldw, int c0,
                       const float* __restrict__ bias,
                       float* __restrict__ C, int R, int K) {
  __shared__ float As[32][200];
  int row0 = blockIdx.y * 32;
  int t = threadIdx.x;
  int r = t >> 3;
  for (int k = (t & 7); k < K; k += 8) {
    int rr = row0 + r;
    As[r][k] = (rr < R) ? A[(size_t)rr * lda + k] : 0.f;
  }
  __syncthreads();
  int c = blockIdx.x * 64 + (t & 63);
  int rb = (t >> 6) << 3;
  if (c >= 200) return;
  const float* Wr = W + (size_t)c * ldw + c0;
  float acc[8] = {0.f, 0.f, 0.f, 0.f, 0.f, 0.f, 0.f, 0.f};
  for (int k = 0; k < K; ++k) {
    float w = Wr[k];
#pragma unroll
    for (int i = 0; i < 8; ++i) acc[i] += As[rb + i][k] * w;
  }
  float bv = bias ? bias[c] : 0.f;
#pragma unroll
  for (int i = 0; i < 8; ++i) {
    int rr = row0 + rb + i;
    if (rr < R) C[(size_t)rr * 200 + c] = acc[i] + bv;
  }
}

// ---------------- CSR build ----------------
__global__ void k_count(const int* __restrict__ row, const int* __restrict__ col,
                        int* __restrict__ cntIn, int* __restrict__ cntOut, int E) {
  int e = blockIdx.x * blockDim.x + threadIdx.x;
  if (e >= E) return;
  atomicAdd(&cntIn[col[e]], 1);
  atomicAdd(&cntOut[row[e]], 1);
}

__global__ void k_scan2(const int* __restrict__ cntA, int* __restrict__ rsA, int* __restrict__ posA,
                        const int* __restrict__ cntB, int* __restrict__ rsB, int* __restrict__ posB,
                        int N) {
  __shared__ int part[1024];
  int t = threadIdx.x;
  for (int d = 0; d < 2; ++d) {
    const int* cnt = d ? cntB : cntA;
    int* rs  = d ? rsB : rsA;
    int* pos = d ? posB : posA;
    int per = (N + 1023) >> 10;
    int beg = t * per;
    int end = min(beg + per, N);
    int s = 0;
    for (int i2 = beg; i2 < end; ++i2) s += cnt[i2];
    part[t] = s;
    __syncthreads();
    for (int off = 1; off < 1024; off <<= 1) {
      int v = (t >= off) ? part[t - off] : 0;
      __syncthreads();
      part[t] += v;
      __syncthreads();
    }
    int run = (t == 0) ? 0 : part[t - 1];
    for (int i2 = beg; i2 < end; ++i2) {
      rs[i2] = run; pos[i2] = run; run += cnt[i2];
    }
    if (t == 1023) rs[N] = part[1023];
    __syncthreads();
  }
}

__global__ void k_fill(const int* __restrict__ row, const int* __restrict__ col,
                       int* __restrict__ posIn, int* __restrict__ posOut,
                       int* __restrict__ lstIn, int* __restrict__ lstOut, int E) {
  int e = blockIdx.x * blockDim.x + threadIdx.x;
  if (e >= E) return;
  int p = atomicAdd(&posIn[col[e]], 1);
  lstIn[p] = e;
  int q = atomicAdd(&posOut[row[e]], 1);
  lstOut[q] = e;
}

// ---------------- u = W^T a  (u[h*Kp+kp] = sum_k a[h*100+k]*W[h*100+k, kp]) ----------------
__global__ void k_makeu(const float* __restrict__ W, int ldw,
                        const float* __restrict__ avec, float* __restrict__ u, int Kp) {
  int idx = blockIdx.x * blockDim.x + threadIdx.x;
  if (idx >= 2 * Kp) return;
  int h = idx / Kp, kp = idx - h * Kp;
  const float* Wb = W + (size_t)(h * 100) * ldw + kp;
  const float* ab = avec + h * 100;
  float s = 0.f;
  for (int k = 0; k < 100; ++k) s += ab[k] * Wb[(size_t)k * ldw];
  u[idx] = s;
}

// ---------------- per-node q dots from input rows (wave per node) ----------------
__global__ void k_qnode(const float* __restrict__ A, int K,
                        const float* __restrict__ uin, const float* __restrict__ uout, int Kp,
                        float* __restrict__ qA, float* __restrict__ qB,
                        float* __restrict__ qC, float* __restrict__ qD, int N) {
  int wid  = (int)((blockIdx.x * (unsigned)blockDim.x + threadIdx.x) >> 6);
  int lane = threadIdx.x & 63;
  if (wid >= N) return;
  const float* a = A + (size_t)wid * K;
  float s[8] = {0.f, 0.f, 0.f, 0.f, 0.f, 0.f, 0.f, 0.f};
  for (int k = lane; k < K; k += 64) {
    float av = a[k];
    s[0] += av * uin[k];
    s[1] += av * uin[Kp + k];
    s[2] += av * uin[K + k];
    s[3] += av * uin[Kp + K + k];
    s[4] += av * uout[k];
    s[5] += av * uout[Kp + k];
    s[6] += av * uout[K + k];
    s[7] += av * uout[Kp + K + k];
  }
#pragma unroll
  for (int m = 1; m < 64; m <<= 1) {
#pragma unroll
    for (int i = 0; i < 8; ++i) s[i] += __shfl_xor(s[i], m, 64);
  }
  if (lane == 0) {
    qA[wid * 2] = s[0]; qA[wid * 2 + 1] = s[1];
    qB[wid * 2] = s[2]; qB[wid * 2 + 1] = s[3];
    qC[wid * 2] = s[4]; qC[wid * 2 + 1] = s[5];
    qD[wid * 2] = s[6]; qD[wid * 2 + 1] = s[7];
  }
}

__global__ void k_qrel(const float* __restrict__ g,
                       const float* __restrict__ uin, const float* __restrict__ uout,
                       int Kp, int off3, float* __restrict__ q3i, float* __restrict__ q3o, int Mn) {
  int wid  = (int)((blockIdx.x * (unsigned)blockDim.x + threadIdx.x) >> 6);
  int lane = threadIdx.x & 63;
  if (wid >= Mn) return;
  const float* a = g + (size_t)wid * 100;
  float s[4] = {0.f, 0.f, 0.f, 0.f};
  for (int k = lane; k < 100; k += 64) {
    float av = a[k];
    s[0] += av * uin[off3 + k];
    s[1] += av * uin[Kp + off3 + k];
    s[2] += av * uout[off3 + k];
    s[3] += av * uout[Kp + off3 + k];
  }
#pragma unroll
  for (int m = 1; m < 64; m <<= 1) {
#pragma unroll
    for (int i = 0; i < 4; ++i) s[i] += __shfl_xor(s[i], m, 64);
  }
  if (lane == 0) {
    q3i[wid * 2] = s[0]; q3i[wid * 2 + 1] = s[1];
    q3o[wid * 2] = s[2]; q3o[wid * 2 + 1] = s[3];
  }
}

// ---------------- per-edge exp(-leakyrelu(logit)) values (no atomics) ----------------
__global__ void k_edge_e(const int* __restrict__ row, const int* __restrict__ col,
                         const int* __restrict__ ety,
                         const float* __restrict__ qA, const float* __restrict__ qB,
                         const float* __restrict__ q3i,
                         const float* __restrict__ qC, const float* __restrict__ qD,
                         const float* __restrict__ q3o,
                         float* __restrict__ eI, float* __restrict__ eO, int E) {
  int e = blockIdx.x * blockDim.x + threadIdx.x;
  if (e >= E) return;
  int r = row[e], c = col[e], t = ety[e];
  float2 vA = *(const float2*)(qA + (size_t)r * 2);
  float2 vB = *(const float2*)(qB + (size_t)c * 2);
  float2 v3 = *(const float2*)(q3i + (size_t)t * 2);
  float2 vC = *(const float2*)(qC + (size_t)r * 2);
  float2 vD = *(const float2*)(qD + (size_t)c * 2);
  float2 v4 = *(const float2*)(q3o + (size_t)t * 2);
  float a0 = vA.x + vB.x + v3.x, a1 = vA.y + vB.y + v3.y;
  float b0 = vC.x + vD.x + v4.x, b1 = vC.y + vD.y + v4.y;
  float2 rI, rO;
  rI.x = expf(-(a0 > 0.f ? a0 : NSLOPE * a0));
  rI.y = expf(-(a1 > 0.f ? a1 : NSLOPE * a1));
  rO.x = expf(-(b0 > 0.f ? b0 : NSLOPE * b0));
  rO.y = expf(-(b1 > 0.f ? b1 : NSLOPE * b1));
  *(float2*)(eI + (size_t)e * 2) = rI;
  *(float2*)(eO + (size_t)e * 2) = rO;
}

// ---------------- fused per-node attention gather + gate + elu + l2 (wave per node) ----------------
__global__ void k_node_att(const int* __restrict__ row, const int* __restrict__ col,
                           const int* __restrict__ ety,
                           const int* __restrict__ rsIn, const int* __restrict__ lstIn,
                           const int* __restrict__ rsOut, const int* __restrict__ lstOut,
                           const float* __restrict__ eI, const float* __restrict__ eO,
                           const float* __restrict__ PA, const float* __restrict__ PB,
                           const float* __restrict__ PC, const float* __restrict__ PD,
                           const float* __restrict__ P3i, const float* __restrict__ P3o,
                           const float* __restrict__ Wg, const float* __restrict__ bg,
                           float* __restrict__ H, int N) {
  int wid  = (int)((blockIdx.x * (unsigned)blockDim.x + threadIdx.x) >> 6);
  int lane = threadIdx.x & 63;
  if (wid >= N) return;
  int n = wid;
  int half = lane >> 5, i = lane & 31;
  bool act = i < 25;
  int j = half * 100 + i * 4;
  float4 accIn = {0.f, 0.f, 0.f, 0.f}, accOut = {0.f, 0.f, 0.f, 0.f};
  if (act) {
    accIn  = *(const float4*)(PB + (size_t)n * 200 + j);
    accOut = *(const float4*)(PC + (size_t)n * 200 + j);
  }
  // ---- IN direction (segment by col; partner = row; sources PA, P3i) ----
  int sIn = rsIn[n];
  int degIn = rsIn[n + 1] - sIn;
  if (degIn > 0) {
    float d0 = 0.f, d1 = 0.f;
    for (int b = 0; b < degIn; b += 64) {
      int l = b + lane;
      float e0 = 0.f, e1 = 0.f;
      if (l < degIn) {
        int e = lstIn[sIn + l];
        float2 ev = *(const float2*)(eI + (size_t)e * 2);
        e0 = ev.x; e1 = ev.y;
      }
#pragma unroll
      for (int m = 1; m < 64; m <<= 1) { e0 += __shfl_xor(e0, m, 64); e1 += __shfl_xor(e1, m, 64); }
      d0 += e0; d1 += e1;
    }
    float invd = 1.f / (half ? d1 : d0);
    for (int b = 0; b < degIn; b += 64) {
      int l = b + lane;
      int r_ = 0, t_ = 0;
      float e0 = 0.f, e1 = 0.f;
      if (l < degIn) {
        int e = lstIn[sIn + l];
        r_ = row[e]; t_ = ety[e];
        float2 ev = *(const float2*)(eI + (size_t)e * 2);
        e0 = ev.x; e1 = ev.y;
      }
      int m2 = min(64, degIn - b);
      for (int jj = 0; jj < m2; ++jj) {
        float a0 = __shfl(e0, jj, 64), a1 = __shfl(e1, jj, 64);
        int re = __shfl(r_, jj, 64), te = __shfl(t_, jj, 64);
        float alpha = (half ? a1 : a0) * invd;
        if (act) {
          float4 pa = *(const float4*)(PA + (size_t)re * 200 + j);
          float4 p3 = *(const float4*)(P3i + (size_t)te * 200 + j);
          accIn.x += alpha * (pa.x + p3.x);
          accIn.y += alpha * (pa.y + p3.y);
          accIn.z += alpha * (pa.z + p3.z);
          accIn.w += alpha * (pa.w + p3.w);
        }
      }
    }
  }
  // ---- OUT direction (segment by row; partner = col; sources PD, P3o) ----
  int sOut = rsOut[n];
  int degOut = rsOut[n + 1] - sOut;
  if (degOut > 0) {
    float d0 = 0.f, d1 = 0.f;
    for (int b = 0; b < degOut; b += 64) {
      int l = b + lane;
      float e0 = 0.f, e1 = 0.f;
      if (l < degOut) {
        int e = lstOut[sOut + l];
        float2 ev = *(const float2*)(eO + (size_t)e * 2);
        e0 = ev.x; e1 = ev.y;
      }
#pragma unroll
      for (int m = 1; m < 64; m <<= 1) { e0 += __shfl_xor(e0, m, 64); e1 += __shfl_xor(e1, m, 64); }
      d0 += e0; d1 += e1;
    }
    float invd = 1.f / (half ? d1 : d0);
    for (int b = 0; b < degOut; b += 64) {
      int l = b + lane;
      int c_ = 0, t_ = 0;
      float e0 = 0.f, e1 = 0.f;
      if (l < degOut) {
        int e = lstOut[sOut + l];
        c_ = col[e]; t_ = ety[e];
        float2 ev = *(const float2*)(eO + (size_t)e * 2);
        e0 = ev.x; e1 = ev.y;
      }
      int m2 = min(64, degOut - b);
      for (int jj = 0; jj < m2; ++jj) {
        float a0 = __shfl(e0, jj, 64), a1 = __shfl(e1, jj, 64);
        int ce = __shfl(c_, jj, 64), te = __shfl(t_, jj, 64);
        float alpha = (half ? a1 : a0) * invd;
        if (act) {
          float4 pd = *(const float4*)(PD + (size_t)ce * 200 + j);
          float4 p3 = *(const float4*)(P3o + (size_t)te * 200 + j);
          accOut.x += alpha * (pd.x + p3.x);
          accOut.y += alpha * (pd.y + p3.y);
          accOut.z += alpha * (pd.z + p3.z);
          accOut.w += alpha * (pd.w + p3.w);
        }
      }
    }
  }
  // ---- gate + elu + per-head l2 ----
  float4 hin, hout;
  hin.x = degIn > 0 ? elu1(accIn.x) : 0.f;
  hin.y = degIn > 0 ? elu1(accIn.y) : 0.f;
  hin.z = degIn > 0 ? elu1(accIn.z) : 0.f;
  hin.w = degIn > 0 ? elu1(accIn.w) : 0.f;
  hout.x = degOut > 0 ? elu1(accOut.x) : 0.f;
  hout.y = degOut > 0 ? elu1(accOut.y) : 0.f;
  hout.z = degOut > 0 ? elu1(accOut.z) : 0.f;
  hout.w = degOut > 0 ? elu1(accOut.w) : 0.f;
  float gp = 0.f;
  if (act) {
    int k = i * 4;
    gp = Wg[k] * hin.x + Wg[k + 1] * hin.y + Wg[k + 2] * hin.z + Wg[k + 3] * hin.w +
         Wg[100 + k] * hout.x + Wg[100 + k + 1] * hout.y +
         Wg[100 + k + 2] * hout.z + Wg[100 + k + 3] * hout.w;
  }
#pragma unroll
  for (int m = 1; m < 32; m <<= 1) gp += __shfl_xor(gp, m, 32);
  float al = 1.f / (1.f + expf(-(gp + bg[0])));
  float4 he;
  he.x = elu1(al * hin.x + (1.f - al) * hout.x);
  he.y = elu1(al * hin.y + (1.f - al) * hout.y);
  he.z = elu1(al * hin.z + (1.f - al) * hout.z);
  he.w = elu1(al * hin.w + (1.f - al) * hout.w);
  float ss = he.x * he.x + he.y * he.y + he.z * he.z + he.w * he.w;
#pragma unroll
  for (int m = 1; m < 32; m <<= 1) ss += __shfl_xor(ss, m, 32);
  float inv = 1.f / fmaxf(sqrtf(ss), 1e-12f);
  if (act) {
    float4 o; o.x = he.x * inv; o.y = he.y * inv; o.z = he.z * inv; o.w = he.w * inv;
    *(float4*)(H + (size_t)n * 200 + j) = o;
  }
}

// ---------------- final: out = l2_perhead(hent + h2) ----------------
__global__ void k_final_norm(const float* __restrict__ hent, const float* __restrict__ h2,
                             float* __restrict__ out, int N) {
  int wid  = (int)((blockIdx.x * (unsigned)blockDim.x + threadIdx.x) >> 6);
  int lane = threadIdx.x & 63;
  if (wid >= N) return;
  int n = wid;
  int half = lane >> 5, i = lane & 31;
  bool act = i < 25;
  int j = half * 100 + i * 4;
  float4 v = {0.f, 0.f, 0.f, 0.f};
  if (act) {
    float4 a = *(const float4*)(hent + (size_t)n * 200 + j);
    float4 b = *(const float4*)(h2 + (size_t)n * 200 + j);
    v.x = a.x + b.x; v.y = a.y + b.y; v.z = a.z + b.z; v.w = a.w + b.w;
  }
  float ss = v.x * v.x + v.y * v.y + v.z * v.z + v.w * v.w;
#pragma unroll
  for (int m = 1; m < 32; m <<= 1) ss += __shfl_xor(ss, m, 32);
  float inv = 1.f / fmaxf(sqrtf(ss), 1e-12f);
  if (act) {
    float4 o; o.x = v.x * inv; o.y = v.y * inv; o.z = v.z * inv; o.w = v.w * inv;
    *(float4*)(out + (size_t)n * 200 + j) = o;
  }
}

extern "C" void kernel_launch(void* const* d_in, const int* in_sizes, int n_in,
                              void* d_out, int out_size, void* d_ws, size_t ws_size,
                              hipStream_t stream) {
  const float* x    = (const float*)d_in[0];
  const float* g    = (const float*)d_in[1];
  const float* W1in = (const float*)d_in[2];
  const float* b1in = (const float*)d_in[3];
  const float* a1in = (const float*)d_in[4];
  const float* W1out= (const float*)d_in[5];
  const float* b1out= (const float*)d_in[6];
  const float* a1out= (const float*)d_in[7];
  const float* Wa1  = (const float*)d_in[8];
  const float* ba1  = (const float*)d_in[9];
  const float* W2in = (const float*)d_in[10];
  const float* b2in = (const float*)d_in[11];
  const float* a2in = (const float*)d_in[12];
  const float* W2out= (const float*)d_in[13];
  const float* b2out= (const float*)d_in[14];
  const float* a2out= (const float*)d_in[15];
  const float* Wa2  = (const float*)d_in[16];
  const float* ba2  = (const float*)d_in[17];
  const float* Went = (const float*)d_in[18];
  const float* bent = (const float*)d_in[19];
  const float* Wrel = (const float*)d_in[20];
  const float* brel = (const float*)d_in[21];
  const int*  eidx  = (const int*)d_in[22];
  const int*  ety   = (const int*)d_in[23];

  const int N = in_sizes[0] / 100;
  const int M = in_sizes[1] / 100;
  const int E = in_sizes[23];
  const int* row = eidx;
  const int* col = eidx + E;
  float* out = (float*)d_out;

  float* ws = (float*)d_ws;
  size_t off = 0;
  auto alloc = [&](size_t nf) { float* p = ws + off; off += (nf + 3) & ~(size_t)3; return p; };
  float* xn  = alloc((size_t)N * 100);
  float* PA  = alloc((size_t)N * 200);
  float* PB  = alloc((size_t)N * 200);
  float* PC  = alloc((size_t)N * 200);
  float* PD  = alloc((size_t)N * 200);
  float* P3i = alloc((size_t)M * 200);
  float* P3o = alloc((size_t)M * 200);
  float* qA  = alloc((size_t)N * 2);
  float* qB  = alloc((size_t)N * 2);
  float* qC  = alloc((size_t)N * 2);
  float* qD  = alloc((size_t)N * 2);
  float* q3i = alloc((size_t)M * 2);
  float* q3o = alloc((size_t)M * 2);
  float* eI  = alloc((size_t)E * 2);
  float* eO  = alloc((size_t)E * 2);
  float* h1  = alloc((size_t)N * 200);
  float* h2  = alloc((size_t)N * 200);
  float* u_in  = alloc(1024);
  float* u_out = alloc(1024);
  int* cntIn  = (int*)alloc((size_t)N);
  int* cntOut = (int*)alloc((size_t)N);
  int* rsIn   = (int*)alloc((size_t)N + 1);
  int* rsOut  = (int*)alloc((size_t)N + 1);
  int* posIn  = (int*)alloc((size_t)N);
  int* posOut = (int*)alloc((size_t)N);
  int* lstIn  = (int*)alloc((size_t)E);
  int* lstOut = (int*)alloc((size_t)E);

  dim3 gg(4, (N + 31) / 32);
  dim3 gm(4, (M + 31) / 32);
  int gN4 = (N + 3) / 4;   // wave-per-node blocks
  int gM4 = (M + 3) / 4;
  int gE  = (E + 255) / 256;

  // ---------- CSR build (once; shared by both layers) ----------
  hipMemsetAsync(cntIn, 0, sizeof(int) * (size_t)N, stream);
  hipMemsetAsync(cntOut, 0, sizeof(int) * (size_t)N, stream);
  k_count<<<gE, 256, 0, stream>>>(row, col, cntIn, cntOut, E);
  k_scan2<<<1, 1024, 0, stream>>>(cntIn, rsIn, posIn, cntOut, rsOut, posOut, N);
  k_fill<<<gE, 256, 0, stream>>>(row, col, posIn, posOut, lstIn, lstOut, E);

  k_l2norm_x<<<gN4, 256, 0, stream>>>(x, xn, N);

  // ---------- layer 1 ----------
  k_makeu<<<3, 256, 0, stream>>>(W1in, 300, a1in, u_in, 300);
  k_makeu<<<3, 256, 0, stream>>>(W1out, 300, a1out, u_out, 300);
  k_qnode<<<gN4, 256, 0, stream>>>(xn, 100, u_in, u_out, 300, qA, qB, qC, qD, N);
  k_qrel<<<gM4, 256, 0, stream>>>(g, u_in, u_out, 300, 200, q3i, q3o, M);
  k_edge_e<<<gE, 256, 0, stream>>>(row, col, ety, qA, qB, q3i, qC, qD, q3o, eI, eO, E);

  k_gemm<<<gg, 256, 0, stream>>>(xn, 100, W1in, 300, 0, nullptr, PA, N, 100);
  k_gemm<<<gg, 256, 0, stream>>>(xn, 100, W1in, 300, 100, nullptr, PB, N, 100);
  k_gemm<<<gg, 256, 0, stream>>>(xn, 100, W1out, 300, 0, nullptr, PC, N, 100);
  k_gemm<<<gg, 256, 0, stream>>>(xn, 100, W1out, 300, 100, nullptr, PD, N, 100);
  k_gemm<<<gm, 256, 0, stream>>>(g, 100, W1in, 300, 200, b1in, P3i, M, 100);
  k_gemm<<<gm, 256, 0, stream>>>(g, 100, W1out, 300, 200, b1out, P3o, M, 100);

  k_node_att<<<gN4, 256, 0, stream>>>(row, col, ety, rsIn, lstIn, rsOut, lstOut,
                                      eI, eO, PA, PB, PC, PD, P3i, P3o, Wa1, ba1, h1, N);

  // ---------- layer 2 ----------
  k_makeu<<<4, 256, 0, stream>>>(W2in, 500, a2in, u_in, 500);
  k_makeu<<<4, 256, 0, stream>>>(W2out, 500, a2out, u_out, 500);
  k_qnode<<<gN4, 256, 0, stream>>>(h1, 200, u_in, u_out, 500, qA, qB, qC, qD, N);
  k_qrel<<<gM4, 256, 0, stream>>>(g, u_in, u_out, 500, 400, q3i, q3o, M);
  k_edge_e<<<gE, 256, 0, stream>>>(row, col, ety, qA, qB, q3i, qC, qD, q3o, eI, eO, E);

  k_gemm<<<gg, 256, 0, stream>>>(h1, 200, W2in, 500, 0, nullptr, PA, N, 200);
  k_gemm<<<gg, 256, 0, stream>>>(h1, 200, W2in, 500, 200, nullptr, PB, N, 200);
  k_gemm<<<gg, 256, 0, stream>>>(h1, 200, W2out, 500, 0, nullptr, PC, N, 200);
  k_gemm<<<gg, 256, 0, stream>>>(h1, 200, W2out, 500, 200, nullptr, PD, N, 200);
  k_gemm<<<gm, 256, 0, stream>>>(g, 100, W2in, 500, 400, b2in, P3i, M, 100);
  k_gemm<<<gm, 256, 0, stream>>>(g, 100, W2out, 500, 400, b2out, P3o, M, 100);

  k_node_att<<<gN4, 256, 0, stream>>>(row, col, ety, rsIn, lstIn, rsOut, lstOut,
                                      eI, eO, PA, PB, PC, PD, P3i, P3o, Wa2, ba2, h2, N);

  // ---------- final ----------
  k_gemm<<<gg, 256, 0, stream>>>(xn, 100, Went, 100, 0, bent, PA, N, 100);
  k_final_norm<<<gN4, 256, 0, stream>>>(PA, h2, out, N);
  k_gemm<<<gm, 256, 0, stream>>>(g, 100, Wrel, 100, 0, brel, out + (size_t)N * 200, M, 100);
}

// Round 3
// 555.029 us; speedup vs baseline: 3.5786x; 1.1732x over previous
//
#include <hip/hip_runtime.h>
#include <math.h>

#define NSLOPE 0.2f

__device__ __forceinline__ float elu1(float x) { return x > 0.f ? x : expm1f(x); }

// ---------------- l2-normalize rows of x [N,100] -> xn ----------------
__global__ void k_l2norm_x(const float* __restrict__ x, float* __restrict__ xn, int N) {
  int wid  = (int)((blockIdx.x * (unsigned)blockDim.x + threadIdx.x) >> 6);
  int lane = threadIdx.x & 63;
  if (wid >= N) return;
  const float* p = x + (size_t)wid * 100;
  float v0 = p[lane];
  float v1 = (lane < 36) ? p[lane + 64] : 0.f;
  float ss = v0 * v0 + v1 * v1;
#pragma unroll
  for (int m = 1; m < 64; m <<= 1) ss += __shfl_xor(ss, m, 64);
  float inv = 1.f / fmaxf(sqrtf(ss), 1e-12f);
  float* o = xn + (size_t)wid * 100;
  o[lane] = v0 * inv;
  if (lane < 36) o[lane + 64] = v1 * inv;
}

// ---------------- fused multi-output GEMM ----------------
// C_o[R,200] = A[R,K] @ W_o.T (+ bias_o), o = 0..NOUT-1. W_o rows have leading
// dim ldw (K-slice offset folded into the pointer). One A-tile stage serves all
// NOUT outputs. LDS reads are wave-broadcast (no bank conflicts).
template <int NOUT>
__global__ void k_gemm_multi(const float* __restrict__ A, int lda,
                             const float* __restrict__ W0, const float* __restrict__ W1,
                             const float* __restrict__ W2, const float* __restrict__ W3,
                             int ldw,
                             const float* __restrict__ b0, const float* __restrict__ b1,
                             const float* __restrict__ b2, const float* __restrict__ b3,
                             float* __restrict__ C0, float* __restrict__ C1,
                             float* __restrict__ C2, float* __restrict__ C3,
                             int R, int K) {
  __shared__ float4 As[32][50];
  int row0 = blockIdx.y * 32;
  int t = threadIdx.x;
  int K4 = K >> 2;
  {
    int r = t >> 3;
    int rr = row0 + r;
    const float4* Ar = (const float4*)(A + (size_t)rr * lda);
    for (int k4 = (t & 7); k4 < K4; k4 += 8)
      As[r][k4] = (rr < R) ? Ar[k4] : make_float4(0.f, 0.f, 0.f, 0.f);
  }
  __syncthreads();
  int c = blockIdx.x * 64 + (t & 63);
  if (c >= 200) return;
  int rb = (t >> 6) << 3;
  const float4* Wr[NOUT];
  Wr[0] = (const float4*)(W0 + (size_t)c * ldw);
  if (NOUT > 1) Wr[1] = (const float4*)(W1 + (size_t)c * ldw);
  if (NOUT > 2) Wr[2] = (const float4*)(W2 + (size_t)c * ldw);
  if (NOUT > 3) Wr[3] = (const float4*)(W3 + (size_t)c * ldw);
  float acc[NOUT][8];
#pragma unroll
  for (int o = 0; o < NOUT; ++o)
#pragma unroll
    for (int i = 0; i < 8; ++i) acc[o][i] = 0.f;
#pragma unroll 2
  for (int k4 = 0; k4 < K4; ++k4) {
    float4 a[8];
#pragma unroll
    for (int i = 0; i < 8; ++i) a[i] = As[rb + i][k4];
#pragma unroll
    for (int o = 0; o < NOUT; ++o) {
      float4 w = Wr[o][k4];
#pragma unroll
      for (int i = 0; i < 8; ++i) {
        acc[o][i] += a[i].x * w.x + a[i].y * w.y + a[i].z * w.z + a[i].w * w.w;
      }
    }
  }
  float bv[NOUT];
  bv[0] = b0 ? b0[c] : 0.f;
  if (NOUT > 1) bv[1] = b1 ? b1[c] : 0.f;
  if (NOUT > 2) bv[2] = b2 ? b2[c] : 0.f;
  if (NOUT > 3) bv[3] = b3 ? b3[c] : 0.f;
  float* Cp[NOUT];
  Cp[0] = C0;
  if (NOUT > 1) Cp[1] = C1;
  if (NOUT > 2) Cp[2] = C2;
  if (NOUT > 3) Cp[3] = C3;
#pragma unroll
  for (int i = 0; i < 8; ++i) {
    int rr = row0 + rb + i;
    if (rr < R) {
#pragma unroll
      for (int o = 0; o < NOUT; ++o) Cp[o][(size_t)rr * 200 + c] = acc[o][i] + bv[o];
    }
  }
}

// ---------------- CSR build ----------------
__global__ void k_count(const int* __restrict__ row, const int* __restrict__ col,
                        int* __restrict__ cntIn, int* __restrict__ cntOut, int E) {
  int e = blockIdx.x * blockDim.x + threadIdx.x;
  if (e >= E) return;
  atomicAdd(&cntIn[col[e]], 1);
  atomicAdd(&cntOut[row[e]], 1);
}

__global__ void k_scan2(const int* __restrict__ cntA, int* __restrict__ rsA, int* __restrict__ posA,
                        const int* __restrict__ cntB, int* __restrict__ rsB, int* __restrict__ posB,
                        int N) {
  __shared__ int part[1024];
  int t = threadIdx.x;
  for (int d = 0; d < 2; ++d) {
    const int* cnt = d ? cntB : cntA;
    int* rs  = d ? rsB : rsA;
    int* pos = d ? posB : posA;
    int per = (N + 1023) >> 10;
    int beg = t * per;
    int end = min(beg + per, N);
    int s = 0;
    for (int i2 = beg; i2 < end; ++i2) s += cnt[i2];
    part[t] = s;
    __syncthreads();
    for (int off = 1; off < 1024; off <<= 1) {
      int v = (t >= off) ? part[t - off] : 0;
      __syncthreads();
      part[t] += v;
      __syncthreads();
    }
    int run = (t == 0) ? 0 : part[t - 1];
    for (int i2 = beg; i2 < end; ++i2) {
      rs[i2] = run; pos[i2] = run; run += cnt[i2];
    }
    if (t == 1023) rs[N] = part[1023];
    __syncthreads();
  }
}

__global__ void k_fill(const int* __restrict__ row, const int* __restrict__ col,
                       int* __restrict__ posIn, int* __restrict__ posOut,
                       int* __restrict__ lstIn, int* __restrict__ lstOut, int E) {
  int e = blockIdx.x * blockDim.x + threadIdx.x;
  if (e >= E) return;
  int p = atomicAdd(&posIn[col[e]], 1);
  lstIn[p] = e;
  int q = atomicAdd(&posOut[row[e]], 1);
  lstOut[q] = e;
}

// ---------------- u = W^T a ----------------
__global__ void k_makeu(const float* __restrict__ W, int ldw,
                        const float* __restrict__ avec, float* __restrict__ u, int Kp) {
  int idx = blockIdx.x * blockDim.x + threadIdx.x;
  if (idx >= 2 * Kp) return;
  int h = idx / Kp, kp = idx - h * Kp;
  const float* Wb = W + (size_t)(h * 100) * ldw + kp;
  const float* ab = avec + h * 100;
  float s = 0.f;
  for (int k = 0; k < 100; ++k) s += ab[k] * Wb[(size_t)k * ldw];
  u[idx] = s;
}

// ---------------- per-node q dots (wave per node) ----------------
__global__ void k_qnode(const float* __restrict__ A, int K,
                        const float* __restrict__ uin, const float* __restrict__ uout, int Kp,
                        float* __restrict__ qA, float* __restrict__ qB,
                        float* __restrict__ qC, float* __restrict__ qD, int N) {
  int wid  = (int)((blockIdx.x * (unsigned)blockDim.x + threadIdx.x) >> 6);
  int lane = threadIdx.x & 63;
  if (wid >= N) return;
  const float* a = A + (size_t)wid * K;
  float s[8] = {0.f, 0.f, 0.f, 0.f, 0.f, 0.f, 0.f, 0.f};
  for (int k = lane; k < K; k += 64) {
    float av = a[k];
    s[0] += av * uin[k];
    s[1] += av * uin[Kp + k];
    s[2] += av * uin[K + k];
    s[3] += av * uin[Kp + K + k];
    s[4] += av * uout[k];
    s[5] += av * uout[Kp + k];
    s[6] += av * uout[K + k];
    s[7] += av * uout[Kp + K + k];
  }
#pragma unroll
  for (int m = 1; m < 64; m <<= 1) {
#pragma unroll
    for (int i = 0; i < 8; ++i) s[i] += __shfl_xor(s[i], m, 64);
  }
  if (lane == 0) {
    qA[wid * 2] = s[0]; qA[wid * 2 + 1] = s[1];
    qB[wid * 2] = s[2]; qB[wid * 2 + 1] = s[3];
    qC[wid * 2] = s[4]; qC[wid * 2 + 1] = s[5];
    qD[wid * 2] = s[6]; qD[wid * 2 + 1] = s[7];
  }
}

__global__ void k_qrel(const float* __restrict__ g,
                       const float* __restrict__ uin, const float* __restrict__ uout,
                       int Kp, int off3, float* __restrict__ q3i, float* __restrict__ q3o, int Mn) {
  int wid  = (int)((blockIdx.x * (unsigned)blockDim.x + threadIdx.x) >> 6);
  int lane = threadIdx.x & 63;
  if (wid >= Mn) return;
  const float* a = g + (size_t)wid * 100;
  float s[4] = {0.f, 0.f, 0.f, 0.f};
  for (int k = lane; k < 100; k += 64) {
    float av = a[k];
    s[0] += av * uin[off3 + k];
    s[1] += av * uin[Kp + off3 + k];
    s[2] += av * uout[off3 + k];
    s[3] += av * uout[Kp + off3 + k];
  }
#pragma unroll
  for (int m = 1; m < 64; m <<= 1) {
#pragma unroll
    for (int i = 0; i < 4; ++i) s[i] += __shfl_xor(s[i], m, 64);
  }
  if (lane == 0) {
    q3i[wid * 2] = s[0]; q3i[wid * 2 + 1] = s[1];
    q3o[wid * 2] = s[2]; q3o[wid * 2 + 1] = s[3];
  }
}

// ---------------- per-edge exp(-leakyrelu(logit)) ----------------
__global__ void k_edge_e(const int* __restrict__ row, const int* __restrict__ col,
                         const int* __restrict__ ety,
                         const float* __restrict__ qA, const float* __restrict__ qB,
                         const float* __restrict__ q3i,
                         const float* __restrict__ qC, const float* __restrict__ qD,
                         const float* __restrict__ q3o,
                         float* __restrict__ eI, float* __restrict__ eO, int E) {
  int e = blockIdx.x * blockDim.x + threadIdx.x;
  if (e >= E) return;
  int r = row[e], c = col[e], t = ety[e];
  float2 vA = *(const float2*)(qA + (size_t)r * 2);
  float2 vB = *(const float2*)(qB + (size_t)c * 2);
  float2 v3 = *(const float2*)(q3i + (size_t)t * 2);
  float2 vC = *(const float2*)(qC + (size_t)r * 2);
  float2 vD = *(const float2*)(qD + (size_t)c * 2);
  float2 v4 = *(const float2*)(q3o + (size_t)t * 2);
  float a0 = vA.x + vB.x + v3.x, a1 = vA.y + vB.y + v3.y;
  float b0 = vC.x + vD.x + v4.x, b1 = vC.y + vD.y + v4.y;
  float2 rI, rO;
  rI.x = expf(-(a0 > 0.f ? a0 : NSLOPE * a0));
  rI.y = expf(-(a1 > 0.f ? a1 : NSLOPE * a1));
  rO.x = expf(-(b0 > 0.f ? b0 : NSLOPE * b0));
  rO.y = expf(-(b1 > 0.f ? b1 : NSLOPE * b1));
  *(float2*)(eI + (size_t)e * 2) = rI;
  *(float2*)(eO + (size_t)e * 2) = rO;
}

// ---------------- fused per-node attention gather + gate + elu + l2 ----------------
__global__ void k_node_att(const int* __restrict__ row, const int* __restrict__ col,
                           const int* __restrict__ ety,
                           const int* __restrict__ rsIn, const int* __restrict__ lstIn,
                           const int* __restrict__ rsOut, const int* __restrict__ lstOut,
                           const float* __restrict__ eI, const float* __restrict__ eO,
                           const float* __restrict__ PA, const float* __restrict__ PB,
                           const float* __restrict__ PC, const float* __restrict__ PD,
                           const float* __restrict__ P3i, const float* __restrict__ P3o,
                           const float* __restrict__ Wg, const float* __restrict__ bg,
                           float* __restrict__ H, int N) {
  int wid  = (int)((blockIdx.x * (unsigned)blockDim.x + threadIdx.x) >> 6);
  int lane = threadIdx.x & 63;
  if (wid >= N) return;
  int n = wid;
  int half = lane >> 5, i = lane & 31;
  bool act = i < 25;
  int j = half * 100 + i * 4;
  float4 accIn = {0.f, 0.f, 0.f, 0.f}, accOut = {0.f, 0.f, 0.f, 0.f};
  if (act) {
    accIn  = *(const float4*)(PB + (size_t)n * 200 + j);
    accOut = *(const float4*)(PC + (size_t)n * 200 + j);
  }
  int sIn = rsIn[n];
  int degIn = rsIn[n + 1] - sIn;
  if (degIn > 0) {
    float d0 = 0.f, d1 = 0.f;
    for (int b = 0; b < degIn; b += 64) {
      int l = b + lane;
      float e0 = 0.f, e1 = 0.f;
      if (l < degIn) {
        int e = lstIn[sIn + l];
        float2 ev = *(const float2*)(eI + (size_t)e * 2);
        e0 = ev.x; e1 = ev.y;
      }
#pragma unroll
      for (int m = 1; m < 64; m <<= 1) { e0 += __shfl_xor(e0, m, 64); e1 += __shfl_xor(e1, m, 64); }
      d0 += e0; d1 += e1;
    }
    float invd = 1.f / (half ? d1 : d0);
    for (int b = 0; b < degIn; b += 64) {
      int l = b + lane;
      int r_ = 0, t_ = 0;
      float e0 = 0.f, e1 = 0.f;
      if (l < degIn) {
        int e = lstIn[sIn + l];
        r_ = row[e]; t_ = ety[e];
        float2 ev = *(const float2*)(eI + (size_t)e * 2);
        e0 = ev.x; e1 = ev.y;
      }
      int m2 = min(64, degIn - b);
      for (int jj = 0; jj < m2; ++jj) {
        float a0 = __shfl(e0, jj, 64), a1 = __shfl(e1, jj, 64);
        int re = __shfl(r_, jj, 64), te = __shfl(t_, jj, 64);
        float alpha = (half ? a1 : a0) * invd;
        if (act) {
          float4 pa = *(const float4*)(PA + (size_t)re * 200 + j);
          float4 p3 = *(const float4*)(P3i + (size_t)te * 200 + j);
          accIn.x += alpha * (pa.x + p3.x);
          accIn.y += alpha * (pa.y + p3.y);
          accIn.z += alpha * (pa.z + p3.z);
          accIn.w += alpha * (pa.w + p3.w);
        }
      }
    }
  }
  int sOut = rsOut[n];
  int degOut = rsOut[n + 1] - sOut;
  if (degOut > 0) {
    float d0 = 0.f, d1 = 0.f;
    for (int b = 0; b < degOut; b += 64) {
      int l = b + lane;
      float e0 = 0.f, e1 = 0.f;
      if (l < degOut) {
        int e = lstOut[sOut + l];
        float2 ev = *(const float2*)(eO + (size_t)e * 2);
        e0 = ev.x; e1 = ev.y;
      }
#pragma unroll
      for (int m = 1; m < 64; m <<= 1) { e0 += __shfl_xor(e0, m, 64); e1 += __shfl_xor(e1, m, 64); }
      d0 += e0; d1 += e1;
    }
    float invd = 1.f / (half ? d1 : d0);
    for (int b = 0; b < degOut; b += 64) {
      int l = b + lane;
      int c_ = 0, t_ = 0;
      float e0 = 0.f, e1 = 0.f;
      if (l < degOut) {
        int e = lstOut[sOut + l];
        c_ = col[e]; t_ = ety[e];
        float2 ev = *(const float2*)(eO + (size_t)e * 2);
        e0 = ev.x; e1 = ev.y;
      }
      int m2 = min(64, degOut - b);
      for (int jj = 0; jj < m2; ++jj) {
        float a0 = __shfl(e0, jj, 64), a1 = __shfl(e1, jj, 64);
        int ce = __shfl(c_, jj, 64), te = __shfl(t_, jj, 64);
        float alpha = (half ? a1 : a0) * invd;
        if (act) {
          float4 pd = *(const float4*)(PD + (size_t)ce * 200 + j);
          float4 p3 = *(const float4*)(P3o + (size_t)te * 200 + j);
          accOut.x += alpha * (pd.x + p3.x);
          accOut.y += alpha * (pd.y + p3.y);
          accOut.z += alpha * (pd.z + p3.z);
          accOut.w += alpha * (pd.w + p3.w);
        }
      }
    }
  }
  float4 hin, hout;
  hin.x = degIn > 0 ? elu1(accIn.x) : 0.f;
  hin.y = degIn > 0 ? elu1(accIn.y) : 0.f;
  hin.z = degIn > 0 ? elu1(accIn.z) : 0.f;
  hin.w = degIn > 0 ? elu1(accIn.w) : 0.f;
  hout.x = degOut > 0 ? elu1(accOut.x) : 0.f;
  hout.y = degOut > 0 ? elu1(accOut.y) : 0.f;
  hout.z = degOut > 0 ? elu1(accOut.z) : 0.f;
  hout.w = degOut > 0 ? elu1(accOut.w) : 0.f;
  float gp = 0.f;
  if (act) {
    int k = i * 4;
    gp = Wg[k] * hin.x + Wg[k + 1] * hin.y + Wg[k + 2] * hin.z + Wg[k + 3] * hin.w +
         Wg[100 + k] * hout.x + Wg[100 + k + 1] * hout.y +
         Wg[100 + k + 2] * hout.z + Wg[100 + k + 3] * hout.w;
  }
#pragma unroll
  for (int m = 1; m < 32; m <<= 1) gp += __shfl_xor(gp, m, 32);
  float al = 1.f / (1.f + expf(-(gp + bg[0])));
  float4 he;
  he.x = elu1(al * hin.x + (1.f - al) * hout.x);
  he.y = elu1(al * hin.y + (1.f - al) * hout.y);
  he.z = elu1(al * hin.z + (1.f - al) * hout.z);
  he.w = elu1(al * hin.w + (1.f - al) * hout.w);
  float ss = he.x * he.x + he.y * he.y + he.z * he.z + he.w * he.w;
#pragma unroll
  for (int m = 1; m < 32; m <<= 1) ss += __shfl_xor(ss, m, 32);
  float inv = 1.f / fmaxf(sqrtf(ss), 1e-12f);
  if (act) {
    float4 o; o.x = he.x * inv; o.y = he.y * inv; o.z = he.z * inv; o.w = he.w * inv;
    *(float4*)(H + (size_t)n * 200 + j) = o;
  }
}

// ---------------- final: out = l2_perhead(hent + h2) ----------------
__global__ void k_final_norm(const float* __restrict__ hent, const float* __restrict__ h2,
                             float* __restrict__ out, int N) {
  int wid  = (int)((blockIdx.x * (unsigned)blockDim.x + threadIdx.x) >> 6);
  int lane = threadIdx.x & 63;
  if (wid >= N) return;
  int n = wid;
  int half = lane >> 5, i = lane & 31;
  bool act = i < 25;
  int j = half * 100 + i * 4;
  float4 v = {0.f, 0.f, 0.f, 0.f};
  if (act) {
    float4 a = *(const float4*)(hent + (size_t)n * 200 + j);
    float4 b = *(const float4*)(h2 + (size_t)n * 200 + j);
    v.x = a.x + b.x; v.y = a.y + b.y; v.z = a.z + b.z; v.w = a.w + b.w;
  }
  float ss = v.x * v.x + v.y * v.y + v.z * v.z + v.w * v.w;
#pragma unroll
  for (int m = 1; m < 32; m <<= 1) ss += __shfl_xor(ss, m, 32);
  float inv = 1.f / fmaxf(sqrtf(ss), 1e-12f);
  if (act) {
    float4 o; o.x = v.x * inv; o.y = v.y * inv; o.z = v.z * inv; o.w = v.w * inv;
    *(float4*)(out + (size_t)n * 200 + j) = o;
  }
}

extern "C" void kernel_launch(void* const* d_in, const int* in_sizes, int n_in,
                              void* d_out, int out_size, void* d_ws, size_t ws_size,
                              hipStream_t stream) {
  const float* x    = (const float*)d_in[0];
  const float* g    = (const float*)d_in[1];
  const float* W1in = (const float*)d_in[2];
  const float* b1in = (const float*)d_in[3];
  const float* a1in = (const float*)d_in[4];
  const float* W1out= (const float*)d_in[5];
  const float* b1out= (const float*)d_in[6];
  const float* a1out= (const float*)d_in[7];
  const float* Wa1  = (const float*)d_in[8];
  const float* ba1  = (const float*)d_in[9];
  const float* W2in = (const float*)d_in[10];
  const float* b2in = (const float*)d_in[11];
  const float* a2in = (const float*)d_in[12];
  const float* W2out= (const float*)d_in[13];
  const float* b2out= (const float*)d_in[14];
  const float* a2out= (const float*)d_in[15];
  const float* Wa2  = (const float*)d_in[16];
  const float* ba2  = (const float*)d_in[17];
  const float* Went = (const float*)d_in[18];
  const float* bent = (const float*)d_in[19];
  const float* Wrel = (const float*)d_in[20];
  const float* brel = (const float*)d_in[21];
  const int*  eidx  = (const int*)d_in[22];
  const int*  ety   = (const int*)d_in[23];

  const int N = in_sizes[0] / 100;
  const int M = in_sizes[1] / 100;
  const int E = in_sizes[23];
  const int* row = eidx;
  const int* col = eidx + E;
  float* out = (float*)d_out;

  float* ws = (float*)d_ws;
  size_t off = 0;
  auto alloc = [&](size_t nf) { float* p = ws + off; off += (nf + 3) & ~(size_t)3; return p; };
  float* xn  = alloc((size_t)N * 100);
  float* PA  = alloc((size_t)N * 200);
  float* PB  = alloc((size_t)N * 200);
  float* PC  = alloc((size_t)N * 200);
  float* PD  = alloc((size_t)N * 200);
  float* P3i = alloc((size_t)M * 200);
  float* P3o = alloc((size_t)M * 200);
  float* qA  = alloc((size_t)N * 2);
  float* qB  = alloc((size_t)N * 2);
  float* qC  = alloc((size_t)N * 2);
  float* qD  = alloc((size_t)N * 2);
  float* q3i = alloc((size_t)M * 2);
  float* q3o = alloc((size_t)M * 2);
  float* eI  = alloc((size_t)E * 2);
  float* eO  = alloc((size_t)E * 2);
  float* h1  = alloc((size_t)N * 200);
  float* h2  = alloc((size_t)N * 200);
  float* u_in  = alloc(1024);
  float* u_out = alloc(1024);
  int* cntIn  = (int*)alloc((size_t)N);
  int* cntOut = (int*)alloc((size_t)N);
  int* rsIn   = (int*)alloc((size_t)N + 1);
  int* rsOut  = (int*)alloc((size_t)N + 1);
  int* posIn  = (int*)alloc((size_t)N);
  int* posOut = (int*)alloc((size_t)N);
  int* lstIn  = (int*)alloc((size_t)E);
  int* lstOut = (int*)alloc((size_t)E);

  dim3 gg(4, (N + 31) / 32);
  dim3 gm(4, (M + 31) / 32);
  int gN4 = (N + 3) / 4;
  int gM4 = (M + 3) / 4;
  int gE  = (E + 255) / 256;

  // ---------- CSR build ----------
  hipMemsetAsync(cntIn, 0, sizeof(int) * (size_t)N, stream);
  hipMemsetAsync(cntOut, 0, sizeof(int) * (size_t)N, stream);
  k_count<<<gE, 256, 0, stream>>>(row, col, cntIn, cntOut, E);
  k_scan2<<<1, 1024, 0, stream>>>(cntIn, rsIn, posIn, cntOut, rsOut, posOut, N);
  k_fill<<<gE, 256, 0, stream>>>(row, col, posIn, posOut, lstIn, lstOut, E);

  k_l2norm_x<<<gN4, 256, 0, stream>>>(x, xn, N);

  // ---------- layer 1 ----------
  k_makeu<<<3, 256, 0, stream>>>(W1in, 300, a1in, u_in, 300);
  k_makeu<<<3, 256, 0, stream>>>(W1out, 300, a1out, u_out, 300);
  k_qnode<<<gN4, 256, 0, stream>>>(xn, 100, u_in, u_out, 300, qA, qB, qC, qD, N);
  k_qrel<<<gM4, 256, 0, stream>>>(g, u_in, u_out, 300, 200, q3i, q3o, M);
  k_edge_e<<<gE, 256, 0, stream>>>(row, col, ety, qA, qB, q3i, qC, qD, q3o, eI, eO, E);

  k_gemm_multi<4><<<gg, 256, 0, stream>>>(xn, 100,
      W1in, W1in + 100, W1out, W1out + 100, 300,
      nullptr, nullptr, nullptr, nullptr, PA, PB, PC, PD, N, 100);
  k_gemm_multi<2><<<gm, 256, 0, stream>>>(g, 100,
      W1in + 200, W1out + 200, nullptr, nullptr, 300,
      b1in, b1out, nullptr, nullptr, P3i, P3o, nullptr, nullptr, M, 100);

  k_node_att<<<gN4, 256, 0, stream>>>(row, col, ety, rsIn, lstIn, rsOut, lstOut,
                                      eI, eO, PA, PB, PC, PD, P3i, P3o, Wa1, ba1, h1, N);

  // ---------- layer 2 ----------
  k_makeu<<<4, 256, 0, stream>>>(W2in, 500, a2in, u_in, 500);
  k_makeu<<<4, 256, 0, stream>>>(W2out, 500, a2out, u_out, 500);
  k_qnode<<<gN4, 256, 0, stream>>>(h1, 200, u_in, u_out, 500, qA, qB, qC, qD, N);
  k_qrel<<<gM4, 256, 0, stream>>>(g, u_in, u_out, 500, 400, q3i, q3o, M);
  k_edge_e<<<gE, 256, 0, stream>>>(row, col, ety, qA, qB, q3i, qC, qD, q3o, eI, eO, E);

  k_gemm_multi<4><<<gg, 256, 0, stream>>>(h1, 200,
      W2in, W2in + 200, W2out, W2out + 200, 500,
      nullptr, nullptr, nullptr, nullptr, PA, PB, PC, PD, N, 200);
  k_gemm_multi<2><<<gm, 256, 0, stream>>>(g, 100,
      W2in + 400, W2out + 400, nullptr, nullptr, 500,
      b2in, b2out, nullptr, nullptr, P3i, P3o, nullptr, nullptr, M, 100);

  k_node_att<<<gN4, 256, 0, stream>>>(row, col, ety, rsIn, lstIn, rsOut, lstOut,
                                      eI, eO, PA, PB, PC, PD, P3i, P3o, Wa2, ba2, h2, N);

  // ---------- final ----------
  k_gemm_multi<1><<<gg, 256, 0, stream>>>(xn, 100,
      Went, nullptr, nullptr, nullptr, 100,
      bent, nullptr, nullptr, nullptr, PA, nullptr, nullptr, nullptr, N, 100);
  k_final_norm<<<gN4, 256, 0, stream>>>(PA, h2, out, N);
  k_gemm_multi<1><<<gm, 256, 0, stream>>>(g, 100,
      Wrel, nullptr, nullptr, nullptr, 100,
      brel, nullptr, nullptr, nullptr, out + (size_t)N * 200, nullptr, nullptr, nullptr, M, 100);
}

// Round 4
// 375.787 us; speedup vs baseline: 5.2856x; 1.4770x over previous
//
#include <hip/hip_runtime.h>
#include <math.h>

#define NSLOPE 0.2f

typedef unsigned short ushort_t;
typedef __attribute__((ext_vector_type(8))) short bf16x8;
typedef __attribute__((ext_vector_type(8))) unsigned short ushort8;
typedef __attribute__((ext_vector_type(4))) float f32x4;

__device__ __forceinline__ float elu1(float x) { return x > 0.f ? x : expm1f(x); }

__device__ __forceinline__ ushort_t f2bf(float f) {
  union { float f; unsigned int u; } v; v.f = f;
  unsigned int r = v.u + 0x7fffu + ((v.u >> 16) & 1u);
  return (ushort_t)(r >> 16);
}

// ---------------- l2-normalize rows of x [N,100] -> xn (f32) + xnb (bf16, stride 128, zero-padded) ----------------
__global__ void k_l2norm_x(const float* __restrict__ x, float* __restrict__ xn,
                           ushort_t* __restrict__ xnb, int N) {
  int wid  = (int)((blockIdx.x * (unsigned)blockDim.x + threadIdx.x) >> 6);
  int lane = threadIdx.x & 63;
  if (wid >= N) return;
  const float* p = x + (size_t)wid * 100;
  float v0 = p[lane];
  float v1 = (lane < 36) ? p[lane + 64] : 0.f;
  float ss = v0 * v0 + v1 * v1;
#pragma unroll
  for (int m = 1; m < 64; m <<= 1) ss += __shfl_xor(ss, m, 64);
  float inv = 1.f / fmaxf(sqrtf(ss), 1e-12f);
  float* o = xn + (size_t)wid * 100;
  o[lane] = v0 * inv;
  if (lane < 36) o[lane + 64] = v1 * inv;
  ushort_t* ob = xnb + (size_t)wid * 128;
  ob[lane] = f2bf(v0 * inv);
  ob[64 + lane] = (lane < 36) ? f2bf(v1 * inv) : (ushort_t)0;
}

// ---------------- build stacked bf16 weight matrices ----------------
// Wcat[ro][k], ro in [0, rows): o=ro/200, cc=ro%200; o 0/1 -> Wa slices, 2/3 -> Wb slices
__global__ void k_build_wcat(const float* __restrict__ Wa, const float* __restrict__ Wb,
                             int ldw, int Kreal, int Kpad, int rows,
                             ushort_t* __restrict__ out) {
  int idx = blockIdx.x * blockDim.x + threadIdx.x;
  if (idx >= rows * Kpad) return;
  int ro = idx / Kpad, k = idx - ro * Kpad;
  float val = 0.f;
  if (ro < 800 && k < Kreal) {
    int o = ro / 200, cc = ro - o * 200;
    const float* W = (o < 2) ? Wa : Wb;
    int kb = (o & 1) * Kreal;
    val = W[(size_t)cc * ldw + kb + k];
  }
  out[idx] = f2bf(val);
}

// Went [200,100] -> [256][128] bf16 zero-padded
__global__ void k_build_went(const float* __restrict__ Went, ushort_t* __restrict__ out) {
  int idx = blockIdx.x * blockDim.x + threadIdx.x;
  if (idx >= 256 * 128) return;
  int ro = idx >> 7, k = idx & 127;
  float val = (ro < 200 && k < 100) ? Went[ro * 100 + k] : 0.f;
  out[idx] = f2bf(val);
}

// ---------------- MFMA GEMM: C[R, NC] = A[R,Kpad]bf16 @ B[ntn*64,Kpad]bf16^T ----------------
// cols mapped: o = c/OUTW, c2 = c%OUTW -> C_o[r*OUTW + c2] (+ bias[c2])
__global__ __launch_bounds__(256) void k_mfma_gemm(
    const ushort_t* __restrict__ Ab, int lda,
    const ushort_t* __restrict__ Bb, int Kpad,
    int R, int NC, int OUTW, const float* __restrict__ bias,
    float* __restrict__ C0, float* __restrict__ C1,
    float* __restrict__ C2, float* __restrict__ C3) {
  __shared__ ushort_t smA[64 * 64];
  __shared__ ushort_t smB[64 * 64];
  const int t = threadIdx.x;
  const int lane = t & 63;
  const int w = t >> 6;
  const int wm = w >> 1, wn = w & 1;
  const int m0 = blockIdx.y * 64;
  const int n0 = blockIdx.x * 64;
  // staging: thread t -> row t>>2, 16-element quarter t&3
  const int srow = t >> 2;
  const int sq = t & 3;
  const int sw3 = srow & 7;
  const int sbase = srow * 64;
  const int so0 = sbase + ((((sq << 1) + 0) ^ sw3) << 3);
  const int so1 = sbase + ((((sq << 1) + 1) ^ sw3) << 3);
  const bool aok = (m0 + srow) < R;
  const ushort_t* Ag = Ab + (size_t)(m0 + srow) * lda + sq * 16;
  const ushort_t* Bg = Bb + (size_t)(n0 + srow) * Kpad + sq * 16;
  const int lswz = lane & 7;
  const int hi = lane >> 4;
  const int rA0 = (wm * 32 + (lane & 15)) * 64;
  const int rB0 = (wn * 32 + (lane & 15)) * 64;
  f32x4 acc[2][2] = {};
  for (int k0 = 0; k0 < Kpad; k0 += 64) {
    ushort8 a0 = {0, 0, 0, 0, 0, 0, 0, 0}, a1 = {0, 0, 0, 0, 0, 0, 0, 0};
    if (aok) {
      a0 = *(const ushort8*)(Ag + k0);
      a1 = *(const ushort8*)(Ag + k0 + 8);
    }
    ushort8 b0 = *(const ushort8*)(Bg + k0);
    ushort8 b1 = *(const ushort8*)(Bg + k0 + 8);
    __syncthreads();
    *(ushort8*)(smA + so0) = a0;
    *(ushort8*)(smA + so1) = a1;
    *(ushort8*)(smB + so0) = b0;
    *(ushort8*)(smB + so1) = b1;
    __syncthreads();
#pragma unroll
    for (int ks = 0; ks < 2; ++ks) {
      int co = (((ks << 2) + hi) ^ lswz) << 3;
      bf16x8 aA = *(const bf16x8*)(smA + rA0 + co);
      bf16x8 aB = *(const bf16x8*)(smA + rA0 + 1024 + co);
      bf16x8 bA = *(const bf16x8*)(smB + rB0 + co);
      bf16x8 bB = *(const bf16x8*)(smB + rB0 + 1024 + co);
      acc[0][0] = __builtin_amdgcn_mfma_f32_16x16x32_bf16(aA, bA, acc[0][0], 0, 0, 0);
      acc[0][1] = __builtin_amdgcn_mfma_f32_16x16x32_bf16(aA, bB, acc[0][1], 0, 0, 0);
      acc[1][0] = __builtin_amdgcn_mfma_f32_16x16x32_bf16(aB, bA, acc[1][0], 0, 0, 0);
      acc[1][1] = __builtin_amdgcn_mfma_f32_16x16x32_bf16(aB, bB, acc[1][1], 0, 0, 0);
    }
  }
  float* Cp[4] = {C0, C1, C2, C3};
#pragma unroll
  for (int mt = 0; mt < 2; ++mt) {
    int rr0 = m0 + wm * 32 + mt * 16 + (lane >> 4) * 4;
#pragma unroll
    for (int nt = 0; nt < 2; ++nt) {
      int cc = n0 + wn * 32 + nt * 16 + (lane & 15);
      if (cc < NC) {
        int o = cc / OUTW;
        int c2 = cc - o * OUTW;
        float bv = bias ? bias[c2] : 0.f;
        float* Cd = Cp[o];
#pragma unroll
        for (int reg = 0; reg < 4; ++reg) {
          int r = rr0 + reg;
          if (r < R) Cd[(size_t)r * OUTW + c2] = acc[mt][nt][reg] + bv;
        }
      }
    }
  }
}

// ---------------- f32 multi-output GEMM (kept for small M-side matmuls) ----------------
template <int NOUT>
__global__ void k_gemm_multi(const float* __restrict__ A, int lda,
                             const float* __restrict__ W0, const float* __restrict__ W1,
                             int ldw,
                             const float* __restrict__ b0, const float* __restrict__ b1,
                             float* __restrict__ C0, float* __restrict__ C1,
                             int R, int K) {
  __shared__ float4 As[32][50];
  int row0 = blockIdx.y * 32;
  int t = threadIdx.x;
  int K4 = K >> 2;
  {
    int r = t >> 3;
    int rr = row0 + r;
    const float4* Ar = (const float4*)(A + (size_t)rr * lda);
    for (int k4 = (t & 7); k4 < K4; k4 += 8)
      As[r][k4] = (rr < R) ? Ar[k4] : make_float4(0.f, 0.f, 0.f, 0.f);
  }
  __syncthreads();
  int c = blockIdx.x * 64 + (t & 63);
  if (c >= 200) return;
  int rb = (t >> 6) << 3;
  const float4* Wr[NOUT];
  Wr[0] = (const float4*)(W0 + (size_t)c * ldw);
  if (NOUT > 1) Wr[1] = (const float4*)(W1 + (size_t)c * ldw);
  float acc[NOUT][8];
#pragma unroll
  for (int o = 0; o < NOUT; ++o)
#pragma unroll
    for (int i = 0; i < 8; ++i) acc[o][i] = 0.f;
#pragma unroll 2
  for (int k4 = 0; k4 < K4; ++k4) {
    float4 a[8];
#pragma unroll
    for (int i = 0; i < 8; ++i) a[i] = As[rb + i][k4];
#pragma unroll
    for (int o = 0; o < NOUT; ++o) {
      float4 wv = Wr[o][k4];
#pragma unroll
      for (int i = 0; i < 8; ++i)
        acc[o][i] += a[i].x * wv.x + a[i].y * wv.y + a[i].z * wv.z + a[i].w * wv.w;
    }
  }
  float bv[NOUT];
  bv[0] = b0 ? b0[c] : 0.f;
  if (NOUT > 1) bv[1] = b1 ? b1[c] : 0.f;
  float* Cp[NOUT];
  Cp[0] = C0;
  if (NOUT > 1) Cp[1] = C1;
#pragma unroll
  for (int i = 0; i < 8; ++i) {
    int rr = row0 + rb + i;
    if (rr < R) {
#pragma unroll
      for (int o = 0; o < NOUT; ++o) Cp[o][(size_t)rr * 200 + c] = acc[o][i] + bv[o];
    }
  }
}

// ---------------- CSR build ----------------
__global__ void k_count(const int* __restrict__ row, const int* __restrict__ col,
                        int* __restrict__ cntIn, int* __restrict__ cntOut, int E) {
  int e = blockIdx.x * blockDim.x + threadIdx.x;
  if (e >= E) return;
  atomicAdd(&cntIn[col[e]], 1);
  atomicAdd(&cntOut[row[e]], 1);
}

__global__ void k_scan2(const int* __restrict__ cntA, int* __restrict__ rsA, int* __restrict__ posA,
                        const int* __restrict__ cntB, int* __restrict__ rsB, int* __restrict__ posB,
                        int N) {
  __shared__ int part[1024];
  int t = threadIdx.x;
  for (int d = 0; d < 2; ++d) {
    const int* cnt = d ? cntB : cntA;
    int* rs  = d ? rsB : rsA;
    int* pos = d ? posB : posA;
    int per = (N + 1023) >> 10;
    int beg = t * per;
    int end = min(beg + per, N);
    int s = 0;
    for (int i2 = beg; i2 < end; ++i2) s += cnt[i2];
    part[t] = s;
    __syncthreads();
    for (int off = 1; off < 1024; off <<= 1) {
      int v = (t >= off) ? part[t - off] : 0;
      __syncthreads();
      part[t] += v;
      __syncthreads();
    }
    int run = (t == 0) ? 0 : part[t - 1];
    for (int i2 = beg; i2 < end; ++i2) {
      rs[i2] = run; pos[i2] = run; run += cnt[i2];
    }
    if (t == 1023) rs[N] = part[1023];
    __syncthreads();
  }
}

__global__ void k_fill(const int* __restrict__ row, const int* __restrict__ col,
                       int* __restrict__ posIn, int* __restrict__ posOut,
                       int* __restrict__ lstIn, int* __restrict__ lstOut, int E) {
  int e = blockIdx.x * blockDim.x + threadIdx.x;
  if (e >= E) return;
  int p = atomicAdd(&posIn[col[e]], 1);
  lstIn[p] = e;
  int q = atomicAdd(&posOut[row[e]], 1);
  lstOut[q] = e;
}

// ---------------- u = W^T a ----------------
__global__ void k_makeu(const float* __restrict__ W, int ldw,
                        const float* __restrict__ avec, float* __restrict__ u, int Kp) {
  int idx = blockIdx.x * blockDim.x + threadIdx.x;
  if (idx >= 2 * Kp) return;
  int h = idx / Kp, kp = idx - h * Kp;
  const float* Wb = W + (size_t)(h * 100) * ldw + kp;
  const float* ab = avec + h * 100;
  float s = 0.f;
  for (int k = 0; k < 100; ++k) s += ab[k] * Wb[(size_t)k * ldw];
  u[idx] = s;
}

// ---------------- per-node q dots (wave per node) ----------------
__global__ void k_qnode(const float* __restrict__ A, int K,
                        const float* __restrict__ uin, const float* __restrict__ uout, int Kp,
                        float* __restrict__ qA, float* __restrict__ qB,
                        float* __restrict__ qC, float* __restrict__ qD, int N) {
  int wid  = (int)((blockIdx.x * (unsigned)blockDim.x + threadIdx.x) >> 6);
  int lane = threadIdx.x & 63;
  if (wid >= N) return;
  const float* a = A + (size_t)wid * K;
  float s[8] = {0.f, 0.f, 0.f, 0.f, 0.f, 0.f, 0.f, 0.f};
  for (int k = lane; k < K; k += 64) {
    float av = a[k];
    s[0] += av * uin[k];
    s[1] += av * uin[Kp + k];
    s[2] += av * uin[K + k];
    s[3] += av * uin[Kp + K + k];
    s[4] += av * uout[k];
    s[5] += av * uout[Kp + k];
    s[6] += av * uout[K + k];
    s[7] += av * uout[Kp + K + k];
  }
#pragma unroll
  for (int m = 1; m < 64; m <<= 1) {
#pragma unroll
    for (int i = 0; i < 8; ++i) s[i] += __shfl_xor(s[i], m, 64);
  }
  if (lane == 0) {
    qA[wid * 2] = s[0]; qA[wid * 2 + 1] = s[1];
    qB[wid * 2] = s[2]; qB[wid * 2 + 1] = s[3];
    qC[wid * 2] = s[4]; qC[wid * 2 + 1] = s[5];
    qD[wid * 2] = s[6]; qD[wid * 2 + 1] = s[7];
  }
}

__global__ void k_qrel(const float* __restrict__ g,
                       const float* __restrict__ uin, const float* __restrict__ uout,
                       int Kp, int off3, float* __restrict__ q3i, float* __restrict__ q3o, int Mn) {
  int wid  = (int)((blockIdx.x * (unsigned)blockDim.x + threadIdx.x) >> 6);
  int lane = threadIdx.x & 63;
  if (wid >= Mn) return;
  const float* a = g + (size_t)wid * 100;
  float s[4] = {0.f, 0.f, 0.f, 0.f};
  for (int k = lane; k < 100; k += 64) {
    float av = a[k];
    s[0] += av * uin[off3 + k];
    s[1] += av * uin[Kp + off3 + k];
    s[2] += av * uout[off3 + k];
    s[3] += av * uout[Kp + off3 + k];
  }
#pragma unroll
  for (int m = 1; m < 64; m <<= 1) {
#pragma unroll
    for (int i = 0; i < 4; ++i) s[i] += __shfl_xor(s[i], m, 64);
  }
  if (lane == 0) {
    q3i[wid * 2] = s[0]; q3i[wid * 2 + 1] = s[1];
    q3o[wid * 2] = s[2]; q3o[wid * 2 + 1] = s[3];
  }
}

// ---------------- per-edge exp(-leakyrelu(logit)) ----------------
__global__ void k_edge_e(const int* __restrict__ row, const int* __restrict__ col,
                         const int* __restrict__ ety,
                         const float* __restrict__ qA, const float* __restrict__ qB,
                         const float* __restrict__ q3i,
                         const float* __restrict__ qC, const float* __restrict__ qD,
                         const float* __restrict__ q3o,
                         float* __restrict__ eI, float* __restrict__ eO, int E) {
  int e = blockIdx.x * blockDim.x + threadIdx.x;
  if (e >= E) return;
  int r = row[e], c = col[e], t = ety[e];
  float2 vA = *(const float2*)(qA + (size_t)r * 2);
  float2 vB = *(const float2*)(qB + (size_t)c * 2);
  float2 v3 = *(const float2*)(q3i + (size_t)t * 2);
  float2 vC = *(const float2*)(qC + (size_t)r * 2);
  float2 vD = *(const float2*)(qD + (size_t)c * 2);
  float2 v4 = *(const float2*)(q3o + (size_t)t * 2);
  float a0 = vA.x + vB.x + v3.x, a1 = vA.y + vB.y + v3.y;
  float b0 = vC.x + vD.x + v4.x, b1 = vC.y + vD.y + v4.y;
  float2 rI, rO;
  rI.x = expf(-(a0 > 0.f ? a0 : NSLOPE * a0));
  rI.y = expf(-(a1 > 0.f ? a1 : NSLOPE * a1));
  rO.x = expf(-(b0 > 0.f ? b0 : NSLOPE * b0));
  rO.y = expf(-(b1 > 0.f ? b1 : NSLOPE * b1));
  *(float2*)(eI + (size_t)e * 2) = rI;
  *(float2*)(eO + (size_t)e * 2) = rO;
}

// ---------------- fused per-node attention gather + gate + elu + l2 ----------------
__global__ void k_node_att(const int* __restrict__ row, const int* __restrict__ col,
                           const int* __restrict__ ety,
                           const int* __restrict__ rsIn, const int* __restrict__ lstIn,
                           const int* __restrict__ rsOut, const int* __restrict__ lstOut,
                           const float* __restrict__ eI, const float* __restrict__ eO,
                           const float* __restrict__ PA, const float* __restrict__ PB,
                           const float* __restrict__ PC, const float* __restrict__ PD,
                           const float* __restrict__ P3i, const float* __restrict__ P3o,
                           const float* __restrict__ Wg, const float* __restrict__ bg,
                           float* __restrict__ H, ushort_t* __restrict__ Hb, int N) {
  int wid  = (int)((blockIdx.x * (unsigned)blockDim.x + threadIdx.x) >> 6);
  int lane = threadIdx.x & 63;
  if (wid >= N) return;
  int n = wid;
  int half = lane >> 5, i = lane & 31;
  bool act = i < 25;
  int j = half * 100 + i * 4;
  float4 accIn = {0.f, 0.f, 0.f, 0.f}, accOut = {0.f, 0.f, 0.f, 0.f};
  if (act) {
    accIn  = *(const float4*)(PB + (size_t)n * 200 + j);
    accOut = *(const float4*)(PC + (size_t)n * 200 + j);
  }
  int sIn = rsIn[n];
  int degIn = rsIn[n + 1] - sIn;
  if (degIn > 0) {
    float d0 = 0.f, d1 = 0.f;
    for (int b = 0; b < degIn; b += 64) {
      int l = b + lane;
      float e0 = 0.f, e1 = 0.f;
      if (l < degIn) {
        int e = lstIn[sIn + l];
        float2 ev = *(const float2*)(eI + (size_t)e * 2);
        e0 = ev.x; e1 = ev.y;
      }
#pragma unroll
      for (int m = 1; m < 64; m <<= 1) { e0 += __shfl_xor(e0, m, 64); e1 += __shfl_xor(e1, m, 64); }
      d0 += e0; d1 += e1;
    }
    float invd = 1.f / (half ? d1 : d0);
    for (int b = 0; b < degIn; b += 64) {
      int l = b + lane;
      int r_ = 0, t_ = 0;
      float e0 = 0.f, e1 = 0.f;
      if (l < degIn) {
        int e = lstIn[sIn + l];
        r_ = row[e]; t_ = ety[e];
        float2 ev = *(const float2*)(eI + (size_t)e * 2);
        e0 = ev.x; e1 = ev.y;
      }
      int m2 = min(64, degIn - b);
      for (int jj = 0; jj < m2; ++jj) {
        float a0 = __shfl(e0, jj, 64), a1 = __shfl(e1, jj, 64);
        int re = __shfl(r_, jj, 64), te = __shfl(t_, jj, 64);
        float alpha = (half ? a1 : a0) * invd;
        if (act) {
          float4 pa = *(const float4*)(PA + (size_t)re * 200 + j);
          float4 p3 = *(const float4*)(P3i + (size_t)te * 200 + j);
          accIn.x += alpha * (pa.x + p3.x);
          accIn.y += alpha * (pa.y + p3.y);
          accIn.z += alpha * (pa.z + p3.z);
          accIn.w += alpha * (pa.w + p3.w);
        }
      }
    }
  }
  int sOut = rsOut[n];
  int degOut = rsOut[n + 1] - sOut;
  if (degOut > 0) {
    float d0 = 0.f, d1 = 0.f;
    for (int b = 0; b < degOut; b += 64) {
      int l = b + lane;
      float e0 = 0.f, e1 = 0.f;
      if (l < degOut) {
        int e = lstOut[sOut + l];
        float2 ev = *(const float2*)(eO + (size_t)e * 2);
        e0 = ev.x; e1 = ev.y;
      }
#pragma unroll
      for (int m = 1; m < 64; m <<= 1) { e0 += __shfl_xor(e0, m, 64); e1 += __shfl_xor(e1, m, 64); }
      d0 += e0; d1 += e1;
    }
    float invd = 1.f / (half ? d1 : d0);
    for (int b = 0; b < degOut; b += 64) {
      int l = b + lane;
      int c_ = 0, t_ = 0;
      float e0 = 0.f, e1 = 0.f;
      if (l < degOut) {
        int e = lstOut[sOut + l];
        c_ = col[e]; t_ = ety[e];
        float2 ev = *(const float2*)(eO + (size_t)e * 2);
        e0 = ev.x; e1 = ev.y;
      }
      int m2 = min(64, degOut - b);
      for (int jj = 0; jj < m2; ++jj) {
        float a0 = __shfl(e0, jj, 64), a1 = __shfl(e1, jj, 64);
        int ce = __shfl(c_, jj, 64), te = __shfl(t_, jj, 64);
        float alpha = (half ? a1 : a0) * invd;
        if (act) {
          float4 pd = *(const float4*)(PD + (size_t)ce * 200 + j);
          float4 p3 = *(const float4*)(P3o + (size_t)te * 200 + j);
          accOut.x += alpha * (pd.x + p3.x);
          accOut.y += alpha * (pd.y + p3.y);
          accOut.z += alpha * (pd.z + p3.z);
          accOut.w += alpha * (pd.w + p3.w);
        }
      }
    }
  }
  float4 hin, hout;
  hin.x = degIn > 0 ? elu1(accIn.x) : 0.f;
  hin.y = degIn > 0 ? elu1(accIn.y) : 0.f;
  hin.z = degIn > 0 ? elu1(accIn.z) : 0.f;
  hin.w = degIn > 0 ? elu1(accIn.w) : 0.f;
  hout.x = degOut > 0 ? elu1(accOut.x) : 0.f;
  hout.y = degOut > 0 ? elu1(accOut.y) : 0.f;
  hout.z = degOut > 0 ? elu1(accOut.z) : 0.f;
  hout.w = degOut > 0 ? elu1(accOut.w) : 0.f;
  float gp = 0.f;
  if (act) {
    int k = i * 4;
    gp = Wg[k] * hin.x + Wg[k + 1] * hin.y + Wg[k + 2] * hin.z + Wg[k + 3] * hin.w +
         Wg[100 + k] * hout.x + Wg[100 + k + 1] * hout.y +
         Wg[100 + k + 2] * hout.z + Wg[100 + k + 3] * hout.w;
  }
#pragma unroll
  for (int m = 1; m < 32; m <<= 1) gp += __shfl_xor(gp, m, 32);
  float al = 1.f / (1.f + expf(-(gp + bg[0])));
  float4 he;
  he.x = elu1(al * hin.x + (1.f - al) * hout.x);
  he.y = elu1(al * hin.y + (1.f - al) * hout.y);
  he.z = elu1(al * hin.z + (1.f - al) * hout.z);
  he.w = elu1(al * hin.w + (1.f - al) * hout.w);
  float ss = he.x * he.x + he.y * he.y + he.z * he.z + he.w * he.w;
#pragma unroll
  for (int m = 1; m < 32; m <<= 1) ss += __shfl_xor(ss, m, 32);
  float inv = 1.f / fmaxf(sqrtf(ss), 1e-12f);
  if (act) {
    float4 o; o.x = he.x * inv; o.y = he.y * inv; o.z = he.z * inv; o.w = he.w * inv;
    *(float4*)(H + (size_t)n * 200 + j) = o;
    if (Hb) {
      ushort_t* hb = Hb + (size_t)n * 256 + j;
      hb[0] = f2bf(o.x); hb[1] = f2bf(o.y); hb[2] = f2bf(o.z); hb[3] = f2bf(o.w);
    }
  }
}

// ---------------- final: out = l2_perhead(hent + h2) ----------------
__global__ void k_final_norm(const float* __restrict__ hent, const float* __restrict__ h2,
                             float* __restrict__ out, int N) {
  int wid  = (int)((blockIdx.x * (unsigned)blockDim.x + threadIdx.x) >> 6);
  int lane = threadIdx.x & 63;
  if (wid >= N) return;
  int n = wid;
  int half = lane >> 5, i = lane & 31;
  bool act = i < 25;
  int j = half * 100 + i * 4;
  float4 v = {0.f, 0.f, 0.f, 0.f};
  if (act) {
    float4 a = *(const float4*)(hent + (size_t)n * 200 + j);
    float4 b = *(const float4*)(h2 + (size_t)n * 200 + j);
    v.x = a.x + b.x; v.y = a.y + b.y; v.z = a.z + b.z; v.w = a.w + b.w;
  }
  float ss = v.x * v.x + v.y * v.y + v.z * v.z + v.w * v.w;
#pragma unroll
  for (int m = 1; m < 32; m <<= 1) ss += __shfl_xor(ss, m, 32);
  float inv = 1.f / fmaxf(sqrtf(ss), 1e-12f);
  if (act) {
    float4 o; o.x = v.x * inv; o.y = v.y * inv; o.z = v.z * inv; o.w = v.w * inv;
    *(float4*)(out + (size_t)n * 200 + j) = o;
  }
}

extern "C" void kernel_launch(void* const* d_in, const int* in_sizes, int n_in,
                              void* d_out, int out_size, void* d_ws, size_t ws_size,
                              hipStream_t stream) {
  const float* x    = (const float*)d_in[0];
  const float* g    = (const float*)d_in[1];
  const float* W1in = (const float*)d_in[2];
  const float* b1in = (const float*)d_in[3];
  const float* a1in = (const float*)d_in[4];
  const float* W1out= (const float*)d_in[5];
  const float* b1out= (const float*)d_in[6];
  const float* a1out= (const float*)d_in[7];
  const float* Wa1  = (const float*)d_in[8];
  const float* ba1  = (const float*)d_in[9];
  const float* W2in = (const float*)d_in[10];
  const float* b2in = (const float*)d_in[11];
  const float* a2in = (const float*)d_in[12];
  const float* W2out= (const float*)d_in[13];
  const float* b2out= (const float*)d_in[14];
  const float* a2out= (const float*)d_in[15];
  const float* Wa2  = (const float*)d_in[16];
  const float* ba2  = (const float*)d_in[17];
  const float* Went = (const float*)d_in[18];
  const float* bent = (const float*)d_in[19];
  const float* Wrel = (const float*)d_in[20];
  const float* brel = (const float*)d_in[21];
  const int*  eidx  = (const int*)d_in[22];
  const int*  ety   = (const int*)d_in[23];

  const int N = in_sizes[0] / 100;
  const int M = in_sizes[1] / 100;
  const int E = in_sizes[23];
  const int* row = eidx;
  const int* col = eidx + E;
  float* out = (float*)d_out;

  float* ws = (float*)d_ws;
  size_t off = 0;
  auto alloc = [&](size_t nf) { float* p = ws + off; off += (nf + 3) & ~(size_t)3; return p; };
  float* xn  = alloc((size_t)N * 100);
  float* PA  = alloc((size_t)N * 200);
  float* PB  = alloc((size_t)N * 200);
  float* PC  = alloc((size_t)N * 200);
  float* PD  = alloc((size_t)N * 200);
  float* P3i = alloc((size_t)M * 200);
  float* P3o = alloc((size_t)M * 200);
  float* qA  = alloc((size_t)N * 2);
  float* qB  = alloc((size_t)N * 2);
  float* qC  = alloc((size_t)N * 2);
  float* qD  = alloc((size_t)N * 2);
  float* q3i = alloc((size_t)M * 2);
  float* q3o = alloc((size_t)M * 2);
  float* eI  = alloc((size_t)E * 2);
  float* eO  = alloc((size_t)E * 2);
  float* h1  = alloc((size_t)N * 200);
  float* h2  = alloc((size_t)N * 200);
  float* u_in  = alloc(1024);
  float* u_out = alloc(1024);
  ushort_t* xnb   = (ushort_t*)alloc((size_t)N * 128 / 2);
  ushort_t* h1b   = (ushort_t*)alloc((size_t)N * 256 / 2);
  ushort_t* wcat1 = (ushort_t*)alloc((size_t)832 * 128 / 2);
  ushort_t* wcat2 = (ushort_t*)alloc((size_t)832 * 256 / 2);
  ushort_t* wentb = (ushort_t*)alloc((size_t)256 * 128 / 2);
  int* cntIn  = (int*)alloc((size_t)N);
  int* cntOut = (int*)alloc((size_t)N);
  int* rsIn   = (int*)alloc((size_t)N + 1);
  int* rsOut  = (int*)alloc((size_t)N + 1);
  int* posIn  = (int*)alloc((size_t)N);
  int* posOut = (int*)alloc((size_t)N);
  int* lstIn  = (int*)alloc((size_t)E);
  int* lstOut = (int*)alloc((size_t)E);

  dim3 gm(4, (M + 31) / 32);
  int gN4 = (N + 3) / 4;
  int gM4 = (M + 3) / 4;
  int gE  = (E + 255) / 256;
  int mT = (N + 63) / 64;          // M-tiles for MFMA
  dim3 gq8(13, mT);                // NC=800
  dim3 gq2(4, mT);                 // NC=200 (Went)

  // ---------- CSR build + conversions ----------
  hipMemsetAsync(cntIn, 0, sizeof(int) * (size_t)N, stream);
  hipMemsetAsync(cntOut, 0, sizeof(int) * (size_t)N, stream);
  hipMemsetAsync(h1b, 0, (size_t)N * 256 * sizeof(ushort_t), stream);
  k_count<<<gE, 256, 0, stream>>>(row, col, cntIn, cntOut, E);
  k_scan2<<<1, 1024, 0, stream>>>(cntIn, rsIn, posIn, cntOut, rsOut, posOut, N);
  k_fill<<<gE, 256, 0, stream>>>(row, col, posIn, posOut, lstIn, lstOut, E);

  k_l2norm_x<<<gN4, 256, 0, stream>>>(x, xn, xnb, N);
  k_build_wcat<<<(832 * 128 + 255) / 256, 256, 0, stream>>>(W1in, W1out, 300, 100, 128, 832, wcat1);
  k_build_wcat<<<(832 * 256 + 255) / 256, 256, 0, stream>>>(W2in, W2out, 500, 200, 256, 832, wcat2);
  k_build_went<<<(256 * 128 + 255) / 256, 256, 0, stream>>>(Went, wentb);

  // ---------- layer 1 ----------
  k_makeu<<<3, 256, 0, stream>>>(W1in, 300, a1in, u_in, 300);
  k_makeu<<<3, 256, 0, stream>>>(W1out, 300, a1out, u_out, 300);
  k_qnode<<<gN4, 256, 0, stream>>>(xn, 100, u_in, u_out, 300, qA, qB, qC, qD, N);
  k_qrel<<<gM4, 256, 0, stream>>>(g, u_in, u_out, 300, 200, q3i, q3o, M);
  k_edge_e<<<gE, 256, 0, stream>>>(row, col, ety, qA, qB, q3i, qC, qD, q3o, eI, eO, E);

  k_mfma_gemm<<<gq8, 256, 0, stream>>>(xnb, 128, wcat1, 128, N, 800, 200, nullptr, PA, PB, PC, PD);
  k_gemm_multi<2><<<gm, 256, 0, stream>>>(g, 100, W1in + 200, W1out + 200, 300,
                                          b1in, b1out, P3i, P3o, M, 100);

  k_node_att<<<gN4, 256, 0, stream>>>(row, col, ety, rsIn, lstIn, rsOut, lstOut,
                                      eI, eO, PA, PB, PC, PD, P3i, P3o, Wa1, ba1, h1, h1b, N);

  // ---------- layer 2 ----------
  k_makeu<<<4, 256, 0, stream>>>(W2in, 500, a2in, u_in, 500);
  k_makeu<<<4, 256, 0, stream>>>(W2out, 500, a2out, u_out, 500);
  k_qnode<<<gN4, 256, 0, stream>>>(h1, 200, u_in, u_out, 500, qA, qB, qC, qD, N);
  k_qrel<<<gM4, 256, 0, stream>>>(g, u_in, u_out, 500, 400, q3i, q3o, M);
  k_edge_e<<<gE, 256, 0, stream>>>(row, col, ety, qA, qB, q3i, qC, qD, q3o, eI, eO, E);

  k_mfma_gemm<<<gq8, 256, 0, stream>>>(h1b, 256, wcat2, 256, N, 800, 200, nullptr, PA, PB, PC, PD);
  k_gemm_multi<2><<<gm, 256, 0, stream>>>(g, 100, W2in + 400, W2out + 400, 500,
                                          b2in, b2out, P3i, P3o, M, 100);

  k_node_att<<<gN4, 256, 0, stream>>>(row, col, ety, rsIn, lstIn, rsOut, lstOut,
                                      eI, eO, PA, PB, PC, PD, P3i, P3o, Wa2, ba2, h2, nullptr, N);

  // ---------- final ----------
  k_mfma_gemm<<<gq2, 256, 0, stream>>>(xnb, 128, wentb, 128, N, 200, 200, bent, PA, nullptr, nullptr, nullptr);
  k_final_norm<<<gN4, 256, 0, stream>>>(PA, h2, out, N);
  k_gemm_multi<1><<<gm, 256, 0, stream>>>(g, 100, Wrel, nullptr, 100,
                                          brel, nullptr, out + (size_t)N * 200, nullptr, M, 100);
}

// Round 5
// 356.421 us; speedup vs baseline: 5.5728x; 1.0543x over previous
//
#include <hip/hip_runtime.h>
#include <math.h>

#define NSLOPE 0.2f

typedef unsigned short ushort_t;
typedef __attribute__((ext_vector_type(8))) short bf16x8;
typedef __attribute__((ext_vector_type(8))) unsigned short ushort8;
typedef __attribute__((ext_vector_type(4))) float f32x4;

__device__ __forceinline__ float elu1(float x) { return x > 0.f ? x : expm1f(x); }

__device__ __forceinline__ ushort_t f2bf(float f) {
  union { float f; unsigned int u; } v; v.f = f;
  unsigned int r = v.u + 0x7fffu + ((v.u >> 16) & 1u);
  return (ushort_t)(r >> 16);
}
__device__ __forceinline__ float bf2f(ushort_t u) {
  union { unsigned int i; float f; } v; v.i = ((unsigned int)u) << 16; return v.f;
}

// ---------------- l2-normalize rows of x [N,100] -> xn (f32) + xnb (bf16, stride 128) ----------------
__global__ void k_l2norm_x(const float* __restrict__ x, float* __restrict__ xn,
                           ushort_t* __restrict__ xnb, int N) {
  int wid  = (int)((blockIdx.x * (unsigned)blockDim.x + threadIdx.x) >> 6);
  int lane = threadIdx.x & 63;
  if (wid >= N) return;
  const float* p = x + (size_t)wid * 100;
  float v0 = p[lane];
  float v1 = (lane < 36) ? p[lane + 64] : 0.f;
  float ss = v0 * v0 + v1 * v1;
#pragma unroll
  for (int m = 1; m < 64; m <<= 1) ss += __shfl_xor(ss, m, 64);
  float inv = 1.f / fmaxf(sqrtf(ss), 1e-12f);
  float* o = xn + (size_t)wid * 100;
  o[lane] = v0 * inv;
  if (lane < 36) o[lane + 64] = v1 * inv;
  ushort_t* ob = xnb + (size_t)wid * 128;
  ob[lane] = f2bf(v0 * inv);
  ob[64 + lane] = (lane < 36) ? f2bf(v1 * inv) : (ushort_t)0;
}

// ---------------- build stacked bf16 weight matrices ----------------
__global__ void k_build_wcat(const float* __restrict__ Wa, const float* __restrict__ Wb,
                             int ldw, int Kreal, int Kpad, int rows,
                             ushort_t* __restrict__ out) {
  int idx = blockIdx.x * blockDim.x + threadIdx.x;
  if (idx >= rows * Kpad) return;
  int ro = idx / Kpad, k = idx - ro * Kpad;
  float val = 0.f;
  if (ro < 800 && k < Kreal) {
    int o = ro / 200, cc = ro - o * 200;
    const float* W = (o < 2) ? Wa : Wb;
    int kb = (o & 1) * Kreal;
    val = W[(size_t)cc * ldw + kb + k];
  }
  out[idx] = f2bf(val);
}

__global__ void k_build_went(const float* __restrict__ Went, ushort_t* __restrict__ out) {
  int idx = blockIdx.x * blockDim.x + threadIdx.x;
  if (idx >= 256 * 128) return;
  int ro = idx >> 7, k = idx & 127;
  float val = (ro < 200 && k < 100) ? Went[ro * 100 + k] : 0.f;
  out[idx] = f2bf(val);
}

// ---------------- MFMA GEMM: C[R, NC] = A[R,Kpad]bf16 @ B[.,Kpad]bf16^T ----------------
// outputs o=0..3 (OUTW cols each). o==0 -> bf16 Bd0 (if set), o==3 -> bf16 Bd3, else f32 Cp[o].
__global__ __launch_bounds__(256) void k_mfma_gemm(
    const ushort_t* __restrict__ Ab, int lda,
    const ushort_t* __restrict__ Bb, int Kpad,
    int R, int NC, int OUTW, const float* __restrict__ bias,
    float* __restrict__ C0, float* __restrict__ C1,
    float* __restrict__ C2, float* __restrict__ C3,
    ushort_t* __restrict__ Bd0, ushort_t* __restrict__ Bd3) {
  __shared__ ushort_t smA[64 * 64];
  __shared__ ushort_t smB[64 * 64];
  const int t = threadIdx.x;
  const int lane = t & 63;
  const int w = t >> 6;
  const int wm = w >> 1, wn = w & 1;
  const int m0 = blockIdx.y * 64;
  const int n0 = blockIdx.x * 64;
  const int srow = t >> 2;
  const int sq = t & 3;
  const int sw3 = srow & 7;
  const int sbase = srow * 64;
  const int so0 = sbase + ((((sq << 1) + 0) ^ sw3) << 3);
  const int so1 = sbase + ((((sq << 1) + 1) ^ sw3) << 3);
  const bool aok = (m0 + srow) < R;
  const ushort_t* Ag = Ab + (size_t)(m0 + srow) * lda + sq * 16;
  const ushort_t* Bg = Bb + (size_t)(n0 + srow) * Kpad + sq * 16;
  const int lswz = lane & 7;
  const int hi = lane >> 4;
  const int rA0 = (wm * 32 + (lane & 15)) * 64;
  const int rB0 = (wn * 32 + (lane & 15)) * 64;
  f32x4 acc[2][2] = {};
  for (int k0 = 0; k0 < Kpad; k0 += 64) {
    ushort8 a0 = {0, 0, 0, 0, 0, 0, 0, 0}, a1 = {0, 0, 0, 0, 0, 0, 0, 0};
    if (aok) {
      a0 = *(const ushort8*)(Ag + k0);
      a1 = *(const ushort8*)(Ag + k0 + 8);
    }
    ushort8 b0 = *(const ushort8*)(Bg + k0);
    ushort8 b1 = *(const ushort8*)(Bg + k0 + 8);
    __syncthreads();
    *(ushort8*)(smA + so0) = a0;
    *(ushort8*)(smA + so1) = a1;
    *(ushort8*)(smB + so0) = b0;
    *(ushort8*)(smB + so1) = b1;
    __syncthreads();
#pragma unroll
    for (int ks = 0; ks < 2; ++ks) {
      int co = (((ks << 2) + hi) ^ lswz) << 3;
      bf16x8 aA = *(const bf16x8*)(smA + rA0 + co);
      bf16x8 aB = *(const bf16x8*)(smA + rA0 + 1024 + co);
      bf16x8 bA = *(const bf16x8*)(smB + rB0 + co);
      bf16x8 bB = *(const bf16x8*)(smB + rB0 + 1024 + co);
      acc[0][0] = __builtin_amdgcn_mfma_f32_16x16x32_bf16(aA, bA, acc[0][0], 0, 0, 0);
      acc[0][1] = __builtin_amdgcn_mfma_f32_16x16x32_bf16(aA, bB, acc[0][1], 0, 0, 0);
      acc[1][0] = __builtin_amdgcn_mfma_f32_16x16x32_bf16(aB, bA, acc[1][0], 0, 0, 0);
      acc[1][1] = __builtin_amdgcn_mfma_f32_16x16x32_bf16(aB, bB, acc[1][1], 0, 0, 0);
    }
  }
  float* Cp[4] = {C0, C1, C2, C3};
#pragma unroll
  for (int mt = 0; mt < 2; ++mt) {
    int rr0 = m0 + wm * 32 + mt * 16 + (lane >> 4) * 4;
#pragma unroll
    for (int nt = 0; nt < 2; ++nt) {
      int cc = n0 + wn * 32 + nt * 16 + (lane & 15);
      if (cc < NC) {
        int o = cc / OUTW;
        int c2 = cc - o * OUTW;
        float bv = bias ? bias[c2] : 0.f;
        ushort_t* Bd = (o == 0) ? Bd0 : ((o == 3) ? Bd3 : nullptr);
        if (Bd) {
#pragma unroll
          for (int reg = 0; reg < 4; ++reg) {
            int r = rr0 + reg;
            if (r < R) Bd[(size_t)r * OUTW + c2] = f2bf(acc[mt][nt][reg] + bv);
          }
        } else {
          float* Cd = Cp[o];
#pragma unroll
          for (int reg = 0; reg < 4; ++reg) {
            int r = rr0 + reg;
            if (r < R) Cd[(size_t)r * OUTW + c2] = acc[mt][nt][reg] + bv;
          }
        }
      }
    }
  }
}

// ---------------- f32 multi-output GEMM (small M-side matmuls) ----------------
template <int NOUT>
__global__ void k_gemm_multi(const float* __restrict__ A, int lda,
                             const float* __restrict__ W0, const float* __restrict__ W1,
                             int ldw,
                             const float* __restrict__ b0, const float* __restrict__ b1,
                             float* __restrict__ C0, float* __restrict__ C1,
                             int R, int K) {
  __shared__ float4 As[32][50];
  int row0 = blockIdx.y * 32;
  int t = threadIdx.x;
  int K4 = K >> 2;
  {
    int r = t >> 3;
    int rr = row0 + r;
    const float4* Ar = (const float4*)(A + (size_t)rr * lda);
    for (int k4 = (t & 7); k4 < K4; k4 += 8)
      As[r][k4] = (rr < R) ? Ar[k4] : make_float4(0.f, 0.f, 0.f, 0.f);
  }
  __syncthreads();
  int c = blockIdx.x * 64 + (t & 63);
  if (c >= 200) return;
  int rb = (t >> 6) << 3;
  const float4* Wr[NOUT];
  Wr[0] = (const float4*)(W0 + (size_t)c * ldw);
  if (NOUT > 1) Wr[1] = (const float4*)(W1 + (size_t)c * ldw);
  float acc[NOUT][8];
#pragma unroll
  for (int o = 0; o < NOUT; ++o)
#pragma unroll
    for (int i = 0; i < 8; ++i) acc[o][i] = 0.f;
#pragma unroll 2
  for (int k4 = 0; k4 < K4; ++k4) {
    float4 a[8];
#pragma unroll
    for (int i = 0; i < 8; ++i) a[i] = As[rb + i][k4];
#pragma unroll
    for (int o = 0; o < NOUT; ++o) {
      float4 wv = Wr[o][k4];
#pragma unroll
      for (int i = 0; i < 8; ++i)
        acc[o][i] += a[i].x * wv.x + a[i].y * wv.y + a[i].z * wv.z + a[i].w * wv.w;
    }
  }
  float bv[NOUT];
  bv[0] = b0 ? b0[c] : 0.f;
  if (NOUT > 1) bv[1] = b1 ? b1[c] : 0.f;
  float* Cp[NOUT];
  Cp[0] = C0;
  if (NOUT > 1) Cp[1] = C1;
#pragma unroll
  for (int i = 0; i < 8; ++i) {
    int rr = row0 + rb + i;
    if (rr < R) {
#pragma unroll
      for (int o = 0; o < NOUT; ++o) Cp[o][(size_t)rr * 200 + c] = acc[o][i] + bv[o];
    }
  }
}

// ---------------- CSR build ----------------
__global__ void k_count(const int* __restrict__ row, const int* __restrict__ col,
                        int* __restrict__ cntIn, int* __restrict__ cntOut, int E) {
  int e = blockIdx.x * blockDim.x + threadIdx.x;
  if (e >= E) return;
  atomicAdd(&cntIn[col[e]], 1);
  atomicAdd(&cntOut[row[e]], 1);
}

__global__ void k_scan2(const int* __restrict__ cntA, int* __restrict__ rsA, int* __restrict__ posA,
                        const int* __restrict__ cntB, int* __restrict__ rsB, int* __restrict__ posB,
                        int N) {
  __shared__ int part[1024];
  int t = threadIdx.x;
  for (int d = 0; d < 2; ++d) {
    const int* cnt = d ? cntB : cntA;
    int* rs  = d ? rsB : rsA;
    int* pos = d ? posB : posA;
    int per = (N + 1023) >> 10;
    int beg = t * per;
    int end = min(beg + per, N);
    int s = 0;
    for (int i2 = beg; i2 < end; ++i2) s += cnt[i2];
    part[t] = s;
    __syncthreads();
    for (int off = 1; off < 1024; off <<= 1) {
      int v = (t >= off) ? part[t - off] : 0;
      __syncthreads();
      part[t] += v;
      __syncthreads();
    }
    int run = (t == 0) ? 0 : part[t - 1];
    for (int i2 = beg; i2 < end; ++i2) {
      rs[i2] = run; pos[i2] = run; run += cnt[i2];
    }
    if (t == 1023) rs[N] = part[1023];
    __syncthreads();
  }
}

__global__ void k_fill(const int* __restrict__ row, const int* __restrict__ col,
                       int* __restrict__ posIn, int* __restrict__ posOut,
                       int* __restrict__ lstIn, int* __restrict__ lstOut, int E) {
  int e = blockIdx.x * blockDim.x + threadIdx.x;
  if (e >= E) return;
  int p = atomicAdd(&posIn[col[e]], 1);
  lstIn[p] = e;
  int q = atomicAdd(&posOut[row[e]], 1);
  lstOut[q] = e;
}

// ---------------- u = W^T a ----------------
__global__ void k_makeu(const float* __restrict__ W, int ldw,
                        const float* __restrict__ avec, float* __restrict__ u, int Kp) {
  int idx = blockIdx.x * blockDim.x + threadIdx.x;
  if (idx >= 2 * Kp) return;
  int h = idx / Kp, kp = idx - h * Kp;
  const float* Wb = W + (size_t)(h * 100) * ldw + kp;
  const float* ab = avec + h * 100;
  float s = 0.f;
  for (int k = 0; k < 100; ++k) s += ab[k] * Wb[(size_t)k * ldw];
  u[idx] = s;
}

// ---------------- per-node q dots (wave per node) ----------------
__global__ void k_qnode(const float* __restrict__ A, int K,
                        const float* __restrict__ uin, const float* __restrict__ uout, int Kp,
                        float* __restrict__ qA, float* __restrict__ qB,
                        float* __restrict__ qC, float* __restrict__ qD, int N) {
  int wid  = (int)((blockIdx.x * (unsigned)blockDim.x + threadIdx.x) >> 6);
  int lane = threadIdx.x & 63;
  if (wid >= N) return;
  const float* a = A + (size_t)wid * K;
  float s[8] = {0.f, 0.f, 0.f, 0.f, 0.f, 0.f, 0.f, 0.f};
  for (int k = lane; k < K; k += 64) {
    float av = a[k];
    s[0] += av * uin[k];
    s[1] += av * uin[Kp + k];
    s[2] += av * uin[K + k];
    s[3] += av * uin[Kp + K + k];
    s[4] += av * uout[k];
    s[5] += av * uout[Kp + k];
    s[6] += av * uout[K + k];
    s[7] += av * uout[Kp + K + k];
  }
#pragma unroll
  for (int m = 1; m < 64; m <<= 1) {
#pragma unroll
    for (int i = 0; i < 8; ++i) s[i] += __shfl_xor(s[i], m, 64);
  }
  if (lane == 0) {
    qA[wid * 2] = s[0]; qA[wid * 2 + 1] = s[1];
    qB[wid * 2] = s[2]; qB[wid * 2 + 1] = s[3];
    qC[wid * 2] = s[4]; qC[wid * 2 + 1] = s[5];
    qD[wid * 2] = s[6]; qD[wid * 2 + 1] = s[7];
  }
}

__global__ void k_qrel(const float* __restrict__ g,
                       const float* __restrict__ uin, const float* __restrict__ uout,
                       int Kp, int off3, float* __restrict__ q3i, float* __restrict__ q3o, int Mn) {
  int wid  = (int)((blockIdx.x * (unsigned)blockDim.x + threadIdx.x) >> 6);
  int lane = threadIdx.x & 63;
  if (wid >= Mn) return;
  const float* a = g + (size_t)wid * 100;
  float s[4] = {0.f, 0.f, 0.f, 0.f};
  for (int k = lane; k < 100; k += 64) {
    float av = a[k];
    s[0] += av * uin[off3 + k];
    s[1] += av * uin[Kp + off3 + k];
    s[2] += av * uout[off3 + k];
    s[3] += av * uout[Kp + off3 + k];
  }
#pragma unroll
  for (int m = 1; m < 64; m <<= 1) {
#pragma unroll
    for (int i = 0; i < 4; ++i) s[i] += __shfl_xor(s[i], m, 64);
  }
  if (lane == 0) {
    q3i[wid * 2] = s[0]; q3i[wid * 2 + 1] = s[1];
    q3o[wid * 2] = s[2]; q3o[wid * 2 + 1] = s[3];
  }
}

// ---------------- per-edge exp(-leakyrelu(logit)) ----------------
__global__ void k_edge_e(const int* __restrict__ row, const int* __restrict__ col,
                         const int* __restrict__ ety,
                         const float* __restrict__ qA, const float* __restrict__ qB,
                         const float* __restrict__ q3i,
                         const float* __restrict__ qC, const float* __restrict__ qD,
                         const float* __restrict__ q3o,
                         float* __restrict__ eI, float* __restrict__ eO, int E) {
  int e = blockIdx.x * blockDim.x + threadIdx.x;
  if (e >= E) return;
  int r = row[e], c = col[e], t = ety[e];
  float2 vA = *(const float2*)(qA + (size_t)r * 2);
  float2 vB = *(const float2*)(qB + (size_t)c * 2);
  float2 v3 = *(const float2*)(q3i + (size_t)t * 2);
  float2 vC = *(const float2*)(qC + (size_t)r * 2);
  float2 vD = *(const float2*)(qD + (size_t)c * 2);
  float2 v4 = *(const float2*)(q3o + (size_t)t * 2);
  float a0 = vA.x + vB.x + v3.x, a1 = vA.y + vB.y + v3.y;
  float b0 = vC.x + vD.x + v4.x, b1 = vC.y + vD.y + v4.y;
  float2 rI, rO;
  rI.x = expf(-(a0 > 0.f ? a0 : NSLOPE * a0));
  rI.y = expf(-(a1 > 0.f ? a1 : NSLOPE * a1));
  rO.x = expf(-(b0 > 0.f ? b0 : NSLOPE * b0));
  rO.y = expf(-(b1 > 0.f ? b1 : NSLOPE * b1));
  *(float2*)(eI + (size_t)e * 2) = rI;
  *(float2*)(eO + (size_t)e * 2) = rO;
}

// ---------------- fused per-node attention gather + gate + elu + l2 ----------------
// PAb/PDb are bf16 (gathered); PB/PC f32 (self term); P3i/P3o f32 (L2-resident)
__global__ void k_node_att(const int* __restrict__ row, const int* __restrict__ col,
                           const int* __restrict__ ety,
                           const int* __restrict__ rsIn, const int* __restrict__ lstIn,
                           const int* __restrict__ rsOut, const int* __restrict__ lstOut,
                           const float* __restrict__ eI, const float* __restrict__ eO,
                           const ushort_t* __restrict__ PAb, const float* __restrict__ PB,
                           const float* __restrict__ PC, const ushort_t* __restrict__ PDb,
                           const float* __restrict__ P3i, const float* __restrict__ P3o,
                           const float* __restrict__ Wg, const float* __restrict__ bg,
                           float* __restrict__ H, ushort_t* __restrict__ Hb, int N) {
  int wid  = (int)((blockIdx.x * (unsigned)blockDim.x + threadIdx.x) >> 6);
  int lane = threadIdx.x & 63;
  if (wid >= N) return;
  int n = wid;
  int half = lane >> 5, i = lane & 31;
  bool act = i < 25;
  int j = half * 100 + i * 4;
  float4 accIn = {0.f, 0.f, 0.f, 0.f}, accOut = {0.f, 0.f, 0.f, 0.f};
  if (act) {
    accIn  = *(const float4*)(PB + (size_t)n * 200 + j);
    accOut = *(const float4*)(PC + (size_t)n * 200 + j);
  }
  int sIn = rsIn[n];
  int degIn = rsIn[n + 1] - sIn;
  if (degIn > 0) {
    float d0 = 0.f, d1 = 0.f;
    for (int b = 0; b < degIn; b += 64) {
      int l = b + lane;
      float e0 = 0.f, e1 = 0.f;
      if (l < degIn) {
        int e = lstIn[sIn + l];
        float2 ev = *(const float2*)(eI + (size_t)e * 2);
        e0 = ev.x; e1 = ev.y;
      }
#pragma unroll
      for (int m = 1; m < 64; m <<= 1) { e0 += __shfl_xor(e0, m, 64); e1 += __shfl_xor(e1, m, 64); }
      d0 += e0; d1 += e1;
    }
    float invd = 1.f / (half ? d1 : d0);
    for (int b = 0; b < degIn; b += 64) {
      int l = b + lane;
      int r_ = 0, t_ = 0;
      float e0 = 0.f, e1 = 0.f;
      if (l < degIn) {
        int e = lstIn[sIn + l];
        r_ = row[e]; t_ = ety[e];
        float2 ev = *(const float2*)(eI + (size_t)e * 2);
        e0 = ev.x; e1 = ev.y;
      }
      int m2 = min(64, degIn - b);
      for (int jj = 0; jj < m2; ++jj) {
        float a0 = __shfl(e0, jj, 64), a1 = __shfl(e1, jj, 64);
        int re = __shfl(r_, jj, 64), te = __shfl(t_, jj, 64);
        float alpha = (half ? a1 : a0) * invd;
        if (act) {
          ushort4 pa = *(const ushort4*)(PAb + (size_t)re * 200 + j);
          float4 p3 = *(const float4*)(P3i + (size_t)te * 200 + j);
          accIn.x += alpha * (bf2f(pa.x) + p3.x);
          accIn.y += alpha * (bf2f(pa.y) + p3.y);
          accIn.z += alpha * (bf2f(pa.z) + p3.z);
          accIn.w += alpha * (bf2f(pa.w) + p3.w);
        }
      }
    }
  }
  int sOut = rsOut[n];
  int degOut = rsOut[n + 1] - sOut;
  if (degOut > 0) {
    float d0 = 0.f, d1 = 0.f;
    for (int b = 0; b < degOut; b += 64) {
      int l = b + lane;
      float e0 = 0.f, e1 = 0.f;
      if (l < degOut) {
        int e = lstOut[sOut + l];
        float2 ev = *(const float2*)(eO + (size_t)e * 2);
        e0 = ev.x; e1 = ev.y;
      }
#pragma unroll
      for (int m = 1; m < 64; m <<= 1) { e0 += __shfl_xor(e0, m, 64); e1 += __shfl_xor(e1, m, 64); }
      d0 += e0; d1 += e1;
    }
    float invd = 1.f / (half ? d1 : d0);
    for (int b = 0; b < degOut; b += 64) {
      int l = b + lane;
      int c_ = 0, t_ = 0;
      float e0 = 0.f, e1 = 0.f;
      if (l < degOut) {
        int e = lstOut[sOut + l];
        c_ = col[e]; t_ = ety[e];
        float2 ev = *(const float2*)(eO + (size_t)e * 2);
        e0 = ev.x; e1 = ev.y;
      }
      int m2 = min(64, degOut - b);
      for (int jj = 0; jj < m2; ++jj) {
        float a0 = __shfl(e0, jj, 64), a1 = __shfl(e1, jj, 64);
        int ce = __shfl(c_, jj, 64), te = __shfl(t_, jj, 64);
        float alpha = (half ? a1 : a0) * invd;
        if (act) {
          ushort4 pd = *(const ushort4*)(PDb + (size_t)ce * 200 + j);
          float4 p3 = *(const float4*)(P3o + (size_t)te * 200 + j);
          accOut.x += alpha * (bf2f(pd.x) + p3.x);
          accOut.y += alpha * (bf2f(pd.y) + p3.y);
          accOut.z += alpha * (bf2f(pd.z) + p3.z);
          accOut.w += alpha * (bf2f(pd.w) + p3.w);
        }
      }
    }
  }
  float4 hin, hout;
  hin.x = degIn > 0 ? elu1(accIn.x) : 0.f;
  hin.y = degIn > 0 ? elu1(accIn.y) : 0.f;
  hin.z = degIn > 0 ? elu1(accIn.z) : 0.f;
  hin.w = degIn > 0 ? elu1(accIn.w) : 0.f;
  hout.x = degOut > 0 ? elu1(accOut.x) : 0.f;
  hout.y = degOut > 0 ? elu1(accOut.y) : 0.f;
  hout.z = degOut > 0 ? elu1(accOut.z) : 0.f;
  hout.w = degOut > 0 ? elu1(accOut.w) : 0.f;
  float gp = 0.f;
  if (act) {
    int k = i * 4;
    gp = Wg[k] * hin.x + Wg[k + 1] * hin.y + Wg[k + 2] * hin.z + Wg[k + 3] * hin.w +
         Wg[100 + k] * hout.x + Wg[100 + k + 1] * hout.y +
         Wg[100 + k + 2] * hout.z + Wg[100 + k + 3] * hout.w;
  }
#pragma unroll
  for (int m = 1; m < 32; m <<= 1) gp += __shfl_xor(gp, m, 32);
  float al = 1.f / (1.f + expf(-(gp + bg[0])));
  float4 he;
  he.x = elu1(al * hin.x + (1.f - al) * hout.x);
  he.y = elu1(al * hin.y + (1.f - al) * hout.y);
  he.z = elu1(al * hin.z + (1.f - al) * hout.z);
  he.w = elu1(al * hin.w + (1.f - al) * hout.w);
  float ss = he.x * he.x + he.y * he.y + he.z * he.z + he.w * he.w;
#pragma unroll
  for (int m = 1; m < 32; m <<= 1) ss += __shfl_xor(ss, m, 32);
  float inv = 1.f / fmaxf(sqrtf(ss), 1e-12f);
  if (act) {
    float4 o; o.x = he.x * inv; o.y = he.y * inv; o.z = he.z * inv; o.w = he.w * inv;
    *(float4*)(H + (size_t)n * 200 + j) = o;
    if (Hb) {
      ushort_t* hb = Hb + (size_t)n * 256 + j;
      hb[0] = f2bf(o.x); hb[1] = f2bf(o.y); hb[2] = f2bf(o.z); hb[3] = f2bf(o.w);
    }
  }
}

// ---------------- final: out = l2_perhead(hent + h2) ----------------
__global__ void k_final_norm(const float* __restrict__ hent, const float* __restrict__ h2,
                             float* __restrict__ out, int N) {
  int wid  = (int)((blockIdx.x * (unsigned)blockDim.x + threadIdx.x) >> 6);
  int lane = threadIdx.x & 63;
  if (wid >= N) return;
  int n = wid;
  int half = lane >> 5, i = lane & 31;
  bool act = i < 25;
  int j = half * 100 + i * 4;
  float4 v = {0.f, 0.f, 0.f, 0.f};
  if (act) {
    float4 a = *(const float4*)(hent + (size_t)n * 200 + j);
    float4 b = *(const float4*)(h2 + (size_t)n * 200 + j);
    v.x = a.x + b.x; v.y = a.y + b.y; v.z = a.z + b.z; v.w = a.w + b.w;
  }
  float ss = v.x * v.x + v.y * v.y + v.z * v.z + v.w * v.w;
#pragma unroll
  for (int m = 1; m < 32; m <<= 1) ss += __shfl_xor(ss, m, 32);
  float inv = 1.f / fmaxf(sqrtf(ss), 1e-12f);
  if (act) {
    float4 o; o.x = v.x * inv; o.y = v.y * inv; o.z = v.z * inv; o.w = v.w * inv;
    *(float4*)(out + (size_t)n * 200 + j) = o;
  }
}

extern "C" void kernel_launch(void* const* d_in, const int* in_sizes, int n_in,
                              void* d_out, int out_size, void* d_ws, size_t ws_size,
                              hipStream_t stream) {
  const float* x    = (const float*)d_in[0];
  const float* g    = (const float*)d_in[1];
  const float* W1in = (const float*)d_in[2];
  const float* b1in = (const float*)d_in[3];
  const float* a1in = (const float*)d_in[4];
  const float* W1out= (const float*)d_in[5];
  const float* b1out= (const float*)d_in[6];
  const float* a1out= (const float*)d_in[7];
  const float* Wa1  = (const float*)d_in[8];
  const float* ba1  = (const float*)d_in[9];
  const float* W2in = (const float*)d_in[10];
  const float* b2in = (const float*)d_in[11];
  const float* a2in = (const float*)d_in[12];
  const float* W2out= (const float*)d_in[13];
  const float* b2out= (const float*)d_in[14];
  const float* a2out= (const float*)d_in[15];
  const float* Wa2  = (const float*)d_in[16];
  const float* ba2  = (const float*)d_in[17];
  const float* Went = (const float*)d_in[18];
  const float* bent = (const float*)d_in[19];
  const float* Wrel = (const float*)d_in[20];
  const float* brel = (const float*)d_in[21];
  const int*  eidx  = (const int*)d_in[22];
  const int*  ety   = (const int*)d_in[23];

  const int N = in_sizes[0] / 100;
  const int M = in_sizes[1] / 100;
  const int E = in_sizes[23];
  const int* row = eidx;
  const int* col = eidx + E;
  float* out = (float*)d_out;

  float* ws = (float*)d_ws;
  size_t off = 0;
  auto alloc = [&](size_t nf) { float* p = ws + off; off += (nf + 3) & ~(size_t)3; return p; };
  float* xn  = alloc((size_t)N * 100);
  ushort_t* PAb = (ushort_t*)alloc((size_t)N * 100);   // N*200 bf16
  float* PB  = alloc((size_t)N * 200);
  float* PC  = alloc((size_t)N * 200);
  ushort_t* PDb = (ushort_t*)alloc((size_t)N * 100);   // N*200 bf16
  float* P3i = alloc((size_t)M * 200);
  float* P3o = alloc((size_t)M * 200);
  float* qA  = alloc((size_t)N * 2);
  float* qB  = alloc((size_t)N * 2);
  float* qC  = alloc((size_t)N * 2);
  float* qD  = alloc((size_t)N * 2);
  float* q3i = alloc((size_t)M * 2);
  float* q3o = alloc((size_t)M * 2);
  float* eI  = alloc((size_t)E * 2);
  float* eO  = alloc((size_t)E * 2);
  float* h1  = alloc((size_t)N * 200);
  float* h2  = alloc((size_t)N * 200);
  float* hent = alloc((size_t)N * 200);
  float* u_in  = alloc(1024);
  float* u_out = alloc(1024);
  ushort_t* xnb   = (ushort_t*)alloc((size_t)N * 128 / 2);
  ushort_t* h1b   = (ushort_t*)alloc((size_t)N * 256 / 2);
  ushort_t* wcat1 = (ushort_t*)alloc((size_t)832 * 128 / 2);
  ushort_t* wcat2 = (ushort_t*)alloc((size_t)832 * 256 / 2);
  ushort_t* wentb = (ushort_t*)alloc((size_t)256 * 128 / 2);
  int* cntIn  = (int*)alloc((size_t)N);
  int* cntOut = (int*)alloc((size_t)N);
  int* rsIn   = (int*)alloc((size_t)N + 1);
  int* rsOut  = (int*)alloc((size_t)N + 1);
  int* posIn  = (int*)alloc((size_t)N);
  int* posOut = (int*)alloc((size_t)N);
  int* lstIn  = (int*)alloc((size_t)E);
  int* lstOut = (int*)alloc((size_t)E);

  dim3 gm(4, (M + 31) / 32);
  int gN4 = (N + 3) / 4;
  int gM4 = (M + 3) / 4;
  int gE  = (E + 255) / 256;
  int mT = (N + 63) / 64;
  dim3 gq8(13, mT);   // NC=800
  dim3 gq2(4, mT);    // NC=200 (Went)

  // ---------- CSR build + conversions ----------
  hipMemsetAsync(cntIn, 0, sizeof(int) * (size_t)N, stream);
  hipMemsetAsync(cntOut, 0, sizeof(int) * (size_t)N, stream);
  hipMemsetAsync(h1b, 0, (size_t)N * 256 * sizeof(ushort_t), stream);
  k_count<<<gE, 256, 0, stream>>>(row, col, cntIn, cntOut, E);
  k_scan2<<<1, 1024, 0, stream>>>(cntIn, rsIn, posIn, cntOut, rsOut, posOut, N);
  k_fill<<<gE, 256, 0, stream>>>(row, col, posIn, posOut, lstIn, lstOut, E);

  k_l2norm_x<<<gN4, 256, 0, stream>>>(x, xn, xnb, N);
  k_build_wcat<<<(832 * 128 + 255) / 256, 256, 0, stream>>>(W1in, W1out, 300, 100, 128, 832, wcat1);
  k_build_wcat<<<(832 * 256 + 255) / 256, 256, 0, stream>>>(W2in, W2out, 500, 200, 256, 832, wcat2);
  k_build_went<<<(256 * 128 + 255) / 256, 256, 0, stream>>>(Went, wentb);

  // ---------- layer 1 ----------
  k_makeu<<<3, 256, 0, stream>>>(W1in, 300, a1in, u_in, 300);
  k_makeu<<<3, 256, 0, stream>>>(W1out, 300, a1out, u_out, 300);
  k_qnode<<<gN4, 256, 0, stream>>>(xn, 100, u_in, u_out, 300, qA, qB, qC, qD, N);
  k_qrel<<<gM4, 256, 0, stream>>>(g, u_in, u_out, 300, 200, q3i, q3o, M);
  k_edge_e<<<gE, 256, 0, stream>>>(row, col, ety, qA, qB, q3i, qC, qD, q3o, eI, eO, E);

  k_mfma_gemm<<<gq8, 256, 0, stream>>>(xnb, 128, wcat1, 128, N, 800, 200, nullptr,
                                       nullptr, PB, PC, nullptr, PAb, PDb);
  k_gemm_multi<2><<<gm, 256, 0, stream>>>(g, 100, W1in + 200, W1out + 200, 300,
                                          b1in, b1out, P3i, P3o, M, 100);

  k_node_att<<<gN4, 256, 0, stream>>>(row, col, ety, rsIn, lstIn, rsOut, lstOut,
                                      eI, eO, PAb, PB, PC, PDb, P3i, P3o, Wa1, ba1, h1, h1b, N);

  // ---------- layer 2 ----------
  k_makeu<<<4, 256, 0, stream>>>(W2in, 500, a2in, u_in, 500);
  k_makeu<<<4, 256, 0, stream>>>(W2out, 500, a2out, u_out, 500);
  k_qnode<<<gN4, 256, 0, stream>>>(h1, 200, u_in, u_out, 500, qA, qB, qC, qD, N);
  k_qrel<<<gM4, 256, 0, stream>>>(g, u_in, u_out, 500, 400, q3i, q3o, M);
  k_edge_e<<<gE, 256, 0, stream>>>(row, col, ety, qA, qB, q3i, qC, qD, q3o, eI, eO, E);

  k_mfma_gemm<<<gq8, 256, 0, stream>>>(h1b, 256, wcat2, 256, N, 800, 200, nullptr,
                                       nullptr, PB, PC, nullptr, PAb, PDb);
  k_gemm_multi<2><<<gm, 256, 0, stream>>>(g, 100, W2in + 400, W2out + 400, 500,
                                          b2in, b2out, P3i, P3o, M, 100);

  k_node_att<<<gN4, 256, 0, stream>>>(row, col, ety, rsIn, lstIn, rsOut, lstOut,
                                      eI, eO, PAb, PB, PC, PDb, P3i, P3o, Wa2, ba2, h2, nullptr, N);

  // ---------- final ----------
  k_mfma_gemm<<<gq2, 256, 0, stream>>>(xnb, 128, wentb, 128, N, 200, 200, bent,
                                       hent, nullptr, nullptr, nullptr, nullptr, nullptr);
  k_final_norm<<<gN4, 256, 0, stream>>>(hent, h2, out, N);
  k_gemm_multi<1><<<gm, 256, 0, stream>>>(g, 100, Wrel, nullptr, 100,
                                          brel, nullptr, out + (size_t)N * 200, nullptr, M, 100);
}

// Round 6
// 309.023 us; speedup vs baseline: 6.4275x; 1.1534x over previous
//
#include <hip/hip_runtime.h>
#include <math.h>

#define NSLOPE 0.2f

typedef unsigned short ushort_t;
typedef __attribute__((ext_vector_type(8))) short bf16x8;
typedef __attribute__((ext_vector_type(8))) unsigned short ushort8;
typedef __attribute__((ext_vector_type(4))) float f32x4;

__device__ __forceinline__ float elu1(float x) { return x > 0.f ? x : expm1f(x); }

__device__ __forceinline__ ushort_t f2bf(float f) {
  union { float f; unsigned int u; } v; v.f = f;
  unsigned int r = v.u + 0x7fffu + ((v.u >> 16) & 1u);
  return (ushort_t)(r >> 16);
}
__device__ __forceinline__ float bf2f(ushort_t u) {
  union { unsigned int i; float f; } v; v.i = ((unsigned int)u) << 16; return v.f;
}

// ---------------- l2norm(x) -> xnb bf16 + layer-1 q dots ----------------
__global__ void k_l2norm_q(const float* __restrict__ x, ushort_t* __restrict__ xnb,
                           const float* __restrict__ u1in, const float* __restrict__ u1out,
                           float* __restrict__ qA, float* __restrict__ qB,
                           float* __restrict__ qC, float* __restrict__ qD, int N) {
  int wid  = (int)((blockIdx.x * (unsigned)blockDim.x + threadIdx.x) >> 6);
  int lane = threadIdx.x & 63;
  if (wid >= N) return;
  const float* p = x + (size_t)wid * 100;
  float v0 = p[lane];
  bool t2 = lane < 36;
  float v1 = t2 ? p[lane + 64] : 0.f;
  float ss = v0 * v0 + v1 * v1;
#pragma unroll
  for (int m = 1; m < 64; m <<= 1) ss += __shfl_xor(ss, m, 64);
  float inv = 1.f / fmaxf(sqrtf(ss), 1e-12f);
  float a0 = v0 * inv, a1 = v1 * inv;
  ushort_t* ob = xnb + (size_t)wid * 128;
  ob[lane] = f2bf(a0);
  ob[64 + lane] = t2 ? f2bf(a1) : (ushort_t)0;
  // q dots: s[0]=A.h0 s[1]=A.h1 s[2]=B.h0 s[3]=B.h1 s[4..7]=out
  int k0 = lane, k1 = 64 + lane;
  float s[8];
  s[0] = a0 * u1in[k0]        + (t2 ? a1 * u1in[k1]        : 0.f);
  s[1] = a0 * u1in[300 + k0]  + (t2 ? a1 * u1in[300 + k1]  : 0.f);
  s[2] = a0 * u1in[100 + k0]  + (t2 ? a1 * u1in[100 + k1]  : 0.f);
  s[3] = a0 * u1in[400 + k0]  + (t2 ? a1 * u1in[400 + k1]  : 0.f);
  s[4] = a0 * u1out[k0]       + (t2 ? a1 * u1out[k1]       : 0.f);
  s[5] = a0 * u1out[300 + k0] + (t2 ? a1 * u1out[300 + k1] : 0.f);
  s[6] = a0 * u1out[100 + k0] + (t2 ? a1 * u1out[100 + k1] : 0.f);
  s[7] = a0 * u1out[400 + k0] + (t2 ? a1 * u1out[400 + k1] : 0.f);
#pragma unroll
  for (int m = 1; m < 64; m <<= 1) {
#pragma unroll
    for (int i = 0; i < 8; ++i) s[i] += __shfl_xor(s[i], m, 64);
  }
  if (lane == 0) {
    qA[wid * 2] = s[0]; qA[wid * 2 + 1] = s[1];
    qB[wid * 2] = s[2]; qB[wid * 2 + 1] = s[3];
    qC[wid * 2] = s[4]; qC[wid * 2 + 1] = s[5];
    qD[wid * 2] = s[6]; qD[wid * 2 + 1] = s[7];
  }
}

// ---------------- combined bf16 weight build (wcat1 | wcat2 | went) ----------------
__global__ void k_build_w(const float* __restrict__ W1in, const float* __restrict__ W1out,
                          const float* __restrict__ W2in, const float* __restrict__ W2out,
                          const float* __restrict__ Went,
                          ushort_t* __restrict__ wcat1, ushort_t* __restrict__ wcat2,
                          ushort_t* __restrict__ wentb) {
  int idx = blockIdx.x * blockDim.x + threadIdx.x;
  const int S1 = 832 * 128, S2 = 832 * 256, S3 = 256 * 128;
  if (idx < S1) {
    int ro = idx >> 7, k = idx & 127;
    float val = 0.f;
    if (ro < 800 && k < 100) {
      int o = ro / 200, cc = ro - o * 200;
      const float* W = (o < 2) ? W1in : W1out;
      val = W[(size_t)cc * 300 + (o & 1) * 100 + k];
    }
    wcat1[idx] = f2bf(val);
  } else if (idx < S1 + S2) {
    int i2 = idx - S1;
    int ro = i2 >> 8, k = i2 & 255;
    float val = 0.f;
    if (ro < 800 && k < 200) {
      int o = ro / 200, cc = ro - o * 200;
      const float* W = (o < 2) ? W2in : W2out;
      val = W[(size_t)cc * 500 + (o & 1) * 200 + k];
    }
    wcat2[i2] = f2bf(val);
  } else if (idx < S1 + S2 + S3) {
    int i3 = idx - S1 - S2;
    int ro = i3 >> 7, k = i3 & 127;
    float val = (ro < 200 && k < 100) ? Went[ro * 100 + k] : 0.f;
    wentb[i3] = f2bf(val);
  }
}

// ---------------- all u = W^T a vectors in one launch ----------------
__global__ void k_makeu_all(const float* __restrict__ W1in, const float* __restrict__ a1in,
                            const float* __restrict__ W1out, const float* __restrict__ a1out,
                            const float* __restrict__ W2in, const float* __restrict__ a2in,
                            const float* __restrict__ W2out, const float* __restrict__ a2out,
                            float* __restrict__ u1in, float* __restrict__ u1out,
                            float* __restrict__ u2in, float* __restrict__ u2out) {
  int idx = blockIdx.x * blockDim.x + threadIdx.x;
  if (idx >= 3200) return;
  const float* W; const float* avec; float* u; int Kp, local;
  if (idx < 600)       { W = W1in;  avec = a1in;  u = u1in;  Kp = 300; local = idx; }
  else if (idx < 1200) { W = W1out; avec = a1out; u = u1out; Kp = 300; local = idx - 600; }
  else if (idx < 2200) { W = W2in;  avec = a2in;  u = u2in;  Kp = 500; local = idx - 1200; }
  else                 { W = W2out; avec = a2out; u = u2out; Kp = 500; local = idx - 2200; }
  int h = local / Kp, kp = local - h * Kp;
  const float* Wb = W + (size_t)(h * 100) * Kp + kp;
  const float* ab = avec + h * 100;
  float s = 0.f;
  for (int k = 0; k < 100; ++k) s += ab[k] * Wb[(size_t)k * Kp];
  u[local] = s;
}

// ---------------- MFMA GEMM: outputs bf16 (Bd) or f32 (C) per slot ----------------
__global__ __launch_bounds__(256) void k_mfma_gemm(
    const ushort_t* __restrict__ Ab, int lda,
    const ushort_t* __restrict__ Bb, int Kpad,
    int R, int NC, int OUTW, const float* __restrict__ bias,
    float* __restrict__ C0,
    ushort_t* __restrict__ Bd0, ushort_t* __restrict__ Bd1,
    ushort_t* __restrict__ Bd2, ushort_t* __restrict__ Bd3) {
  __shared__ ushort_t smA[64 * 64];
  __shared__ ushort_t smB[64 * 64];
  const int t = threadIdx.x;
  const int lane = t & 63;
  const int w = t >> 6;
  const int wm = w >> 1, wn = w & 1;
  const int m0 = blockIdx.y * 64;
  const int n0 = blockIdx.x * 64;
  const int srow = t >> 2;
  const int sq = t & 3;
  const int sw3 = srow & 7;
  const int sbase = srow * 64;
  const int so0 = sbase + ((((sq << 1) + 0) ^ sw3) << 3);
  const int so1 = sbase + ((((sq << 1) + 1) ^ sw3) << 3);
  const bool aok = (m0 + srow) < R;
  const ushort_t* Ag = Ab + (size_t)(m0 + srow) * lda + sq * 16;
  const ushort_t* Bg = Bb + (size_t)(n0 + srow) * Kpad + sq * 16;
  const int lswz = lane & 7;
  const int hi = lane >> 4;
  const int rA0 = (wm * 32 + (lane & 15)) * 64;
  const int rB0 = (wn * 32 + (lane & 15)) * 64;
  f32x4 acc[2][2] = {};
  for (int k0 = 0; k0 < Kpad; k0 += 64) {
    ushort8 a0 = {0, 0, 0, 0, 0, 0, 0, 0}, a1 = {0, 0, 0, 0, 0, 0, 0, 0};
    if (aok) {
      a0 = *(const ushort8*)(Ag + k0);
      a1 = *(const ushort8*)(Ag + k0 + 8);
    }
    ushort8 b0 = *(const ushort8*)(Bg + k0);
    ushort8 b1 = *(const ushort8*)(Bg + k0 + 8);
    __syncthreads();
    *(ushort8*)(smA + so0) = a0;
    *(ushort8*)(smA + so1) = a1;
    *(ushort8*)(smB + so0) = b0;
    *(ushort8*)(smB + so1) = b1;
    __syncthreads();
#pragma unroll
    for (int ks = 0; ks < 2; ++ks) {
      int co = (((ks << 2) + hi) ^ lswz) << 3;
      bf16x8 aA = *(const bf16x8*)(smA + rA0 + co);
      bf16x8 aB = *(const bf16x8*)(smA + rA0 + 1024 + co);
      bf16x8 bA = *(const bf16x8*)(smB + rB0 + co);
      bf16x8 bB = *(const bf16x8*)(smB + rB0 + 1024 + co);
      acc[0][0] = __builtin_amdgcn_mfma_f32_16x16x32_bf16(aA, bA, acc[0][0], 0, 0, 0);
      acc[0][1] = __builtin_amdgcn_mfma_f32_16x16x32_bf16(aA, bB, acc[0][1], 0, 0, 0);
      acc[1][0] = __builtin_amdgcn_mfma_f32_16x16x32_bf16(aB, bA, acc[1][0], 0, 0, 0);
      acc[1][1] = __builtin_amdgcn_mfma_f32_16x16x32_bf16(aB, bB, acc[1][1], 0, 0, 0);
    }
  }
  ushort_t* Bds[4] = {Bd0, Bd1, Bd2, Bd3};
#pragma unroll
  for (int mt = 0; mt < 2; ++mt) {
    int rr0 = m0 + wm * 32 + mt * 16 + (lane >> 4) * 4;
#pragma unroll
    for (int nt = 0; nt < 2; ++nt) {
      int cc = n0 + wn * 32 + nt * 16 + (lane & 15);
      if (cc < NC) {
        int o = cc / OUTW;
        int c2 = cc - o * OUTW;
        float bv = bias ? bias[c2] : 0.f;
        ushort_t* Bd = Bds[o];
        if (Bd) {
#pragma unroll
          for (int reg = 0; reg < 4; ++reg) {
            int r = rr0 + reg;
            if (r < R) Bd[(size_t)r * OUTW + c2] = f2bf(acc[mt][nt][reg] + bv);
          }
        } else {
#pragma unroll
          for (int reg = 0; reg < 4; ++reg) {
            int r = rr0 + reg;
            if (r < R) C0[(size_t)r * OUTW + c2] = acc[mt][nt][reg] + bv;
          }
        }
      }
    }
  }
}

// ---------------- f32-in multi-output GEMM (M-side); BF selects bf16 store ----------------
template <int NOUT, int BF>
__global__ void k_gemm_multi(const float* __restrict__ A, int lda,
                             const float* __restrict__ W0, const float* __restrict__ W1,
                             int ldw,
                             const float* __restrict__ b0, const float* __restrict__ b1,
                             void* __restrict__ C0v, void* __restrict__ C1v,
                             int R, int K) {
  __shared__ float4 As[32][50];
  int row0 = blockIdx.y * 32;
  int t = threadIdx.x;
  int K4 = K >> 2;
  {
    int r = t >> 3;
    int rr = row0 + r;
    const float4* Ar = (const float4*)(A + (size_t)rr * lda);
    for (int k4 = (t & 7); k4 < K4; k4 += 8)
      As[r][k4] = (rr < R) ? Ar[k4] : make_float4(0.f, 0.f, 0.f, 0.f);
  }
  __syncthreads();
  int c = blockIdx.x * 64 + (t & 63);
  if (c >= 200) return;
  int rb = (t >> 6) << 3;
  const float4* Wr[NOUT];
  Wr[0] = (const float4*)(W0 + (size_t)c * ldw);
  if (NOUT > 1) Wr[1] = (const float4*)(W1 + (size_t)c * ldw);
  float acc[NOUT][8];
#pragma unroll
  for (int o = 0; o < NOUT; ++o)
#pragma unroll
    for (int i = 0; i < 8; ++i) acc[o][i] = 0.f;
#pragma unroll 2
  for (int k4 = 0; k4 < K4; ++k4) {
    float4 a[8];
#pragma unroll
    for (int i = 0; i < 8; ++i) a[i] = As[rb + i][k4];
#pragma unroll
    for (int o = 0; o < NOUT; ++o) {
      float4 wv = Wr[o][k4];
#pragma unroll
      for (int i = 0; i < 8; ++i)
        acc[o][i] += a[i].x * wv.x + a[i].y * wv.y + a[i].z * wv.z + a[i].w * wv.w;
    }
  }
  float bv[NOUT];
  bv[0] = b0 ? b0[c] : 0.f;
  if (NOUT > 1) bv[1] = b1 ? b1[c] : 0.f;
  void* Cp[NOUT];
  Cp[0] = C0v;
  if (NOUT > 1) Cp[1] = C1v;
#pragma unroll
  for (int i = 0; i < 8; ++i) {
    int rr = row0 + rb + i;
    if (rr < R) {
#pragma unroll
      for (int o = 0; o < NOUT; ++o) {
        float val = acc[o][i] + bv[o];
        if (BF) ((ushort_t*)Cp[o])[(size_t)rr * 200 + c] = f2bf(val);
        else    ((float*)Cp[o])[(size_t)rr * 200 + c] = val;
      }
    }
  }
}

// ---------------- CSR build ----------------
__global__ void k_count(const int* __restrict__ row, const int* __restrict__ col,
                        int* __restrict__ cntIn, int* __restrict__ cntOut, int E) {
  int e = blockIdx.x * blockDim.x + threadIdx.x;
  if (e >= E) return;
  atomicAdd(&cntIn[col[e]], 1);
  atomicAdd(&cntOut[row[e]], 1);
}

__global__ void k_scan2(const int* __restrict__ cntA, int* __restrict__ rsA, int* __restrict__ posA,
                        const int* __restrict__ cntB, int* __restrict__ rsB, int* __restrict__ posB,
                        int N) {
  __shared__ int part[1024];
  int t = threadIdx.x;
  for (int d = 0; d < 2; ++d) {
    const int* cnt = d ? cntB : cntA;
    int* rs  = d ? rsB : rsA;
    int* pos = d ? posB : posA;
    int per = (N + 1023) >> 10;
    int beg = t * per;
    int end = min(beg + per, N);
    int s = 0;
    for (int i2 = beg; i2 < end; ++i2) s += cnt[i2];
    part[t] = s;
    __syncthreads();
    for (int off = 1; off < 1024; off <<= 1) {
      int v = (t >= off) ? part[t - off] : 0;
      __syncthreads();
      part[t] += v;
      __syncthreads();
    }
    int run = (t == 0) ? 0 : part[t - 1];
    for (int i2 = beg; i2 < end; ++i2) {
      rs[i2] = run; pos[i2] = run; run += cnt[i2];
    }
    if (t == 1023) rs[N] = part[1023];
    __syncthreads();
  }
}

// fill CSR-ordered (partner,type) arrays + edge->pos inverse maps
__global__ void k_fill(const int* __restrict__ row, const int* __restrict__ col,
                       const int* __restrict__ ety,
                       int* __restrict__ posIn, int* __restrict__ posOut,
                       int2* __restrict__ pinIn, int2* __restrict__ pinOut,
                       int* __restrict__ invIn, int* __restrict__ invOut, int E) {
  int e = blockIdx.x * blockDim.x + threadIdx.x;
  if (e >= E) return;
  int r = row[e], c = col[e], tt = ety[e];
  int p = atomicAdd(&posIn[c], 1);
  pinIn[p] = make_int2(r, tt);
  invIn[e] = p;
  int q = atomicAdd(&posOut[r], 1);
  pinOut[q] = make_int2(c, tt);
  invOut[e] = q;
}

// ---------------- per-node q3 dots for both layers ----------------
__global__ void k_qrel2(const float* __restrict__ g,
                        const float* __restrict__ u1in, const float* __restrict__ u1out,
                        const float* __restrict__ u2in, const float* __restrict__ u2out,
                        float* __restrict__ q3i1, float* __restrict__ q3o1,
                        float* __restrict__ q3i2, float* __restrict__ q3o2, int Mn) {
  int wid  = (int)((blockIdx.x * (unsigned)blockDim.x + threadIdx.x) >> 6);
  int lane = threadIdx.x & 63;
  if (wid >= 2 * Mn) return;
  int lay = wid >= Mn;
  int m = wid - lay * Mn;
  const float* uin  = lay ? u2in  : u1in;
  const float* uout = lay ? u2out : u1out;
  int Kp = lay ? 500 : 300;
  int off3 = lay ? 400 : 200;
  float* q3i = lay ? q3i2 : q3i1;
  float* q3o = lay ? q3o2 : q3o1;
  const float* a = g + (size_t)m * 100;
  float s[4] = {0.f, 0.f, 0.f, 0.f};
  for (int k = lane; k < 100; k += 64) {
    float av = a[k];
    s[0] += av * uin[off3 + k];
    s[1] += av * uin[Kp + off3 + k];
    s[2] += av * uout[off3 + k];
    s[3] += av * uout[Kp + off3 + k];
  }
#pragma unroll
  for (int mm = 1; mm < 64; mm <<= 1) {
#pragma unroll
    for (int i = 0; i < 4; ++i) s[i] += __shfl_xor(s[i], mm, 64);
  }
  if (lane == 0) {
    q3i[m * 2] = s[0]; q3i[m * 2 + 1] = s[1];
    q3o[m * 2] = s[2]; q3o[m * 2 + 1] = s[3];
  }
}

// ---------------- per-edge e-values scattered into CSR order ----------------
__global__ void k_edge_e(const int* __restrict__ row, const int* __restrict__ col,
                         const int* __restrict__ ety,
                         const float* __restrict__ qA, const float* __restrict__ qB,
                         const float* __restrict__ q3i,
                         const float* __restrict__ qC, const float* __restrict__ qD,
                         const float* __restrict__ q3o,
                         const int* __restrict__ invIn, const int* __restrict__ invOut,
                         float2* __restrict__ eIc, float2* __restrict__ eOc, int E) {
  int e = blockIdx.x * blockDim.x + threadIdx.x;
  if (e >= E) return;
  int r = row[e], c = col[e], t = ety[e];
  float2 vA = *(const float2*)(qA + (size_t)r * 2);
  float2 vB = *(const float2*)(qB + (size_t)c * 2);
  float2 v3 = *(const float2*)(q3i + (size_t)t * 2);
  float2 vC = *(const float2*)(qC + (size_t)r * 2);
  float2 vD = *(const float2*)(qD + (size_t)c * 2);
  float2 v4 = *(const float2*)(q3o + (size_t)t * 2);
  float a0 = vA.x + vB.x + v3.x, a1 = vA.y + vB.y + v3.y;
  float b0 = vC.x + vD.x + v4.x, b1 = vC.y + vD.y + v4.y;
  float2 rI, rO;
  rI.x = expf(-(a0 > 0.f ? a0 : NSLOPE * a0));
  rI.y = expf(-(a1 > 0.f ? a1 : NSLOPE * a1));
  rO.x = expf(-(b0 > 0.f ? b0 : NSLOPE * b0));
  rO.y = expf(-(b1 > 0.f ? b1 : NSLOPE * b1));
  eIc[invIn[e]] = rI;
  eOc[invOut[e]] = rO;
}

// ---------------- fused per-node attention + gate + elu + l2 (+ next-layer q) ----------------
__global__ void k_node_att(const int2* __restrict__ pinIn, const float2* __restrict__ eIc,
                           const int* __restrict__ rsIn,
                           const int2* __restrict__ pinOut, const float2* __restrict__ eOc,
                           const int* __restrict__ rsOut,
                           const ushort_t* __restrict__ PAb, const ushort_t* __restrict__ PBb,
                           const ushort_t* __restrict__ PCb, const ushort_t* __restrict__ PDb,
                           const ushort_t* __restrict__ P3ib, const ushort_t* __restrict__ P3ob,
                           const float* __restrict__ Wg, const float* __restrict__ bg,
                           const float* __restrict__ u2in, const float* __restrict__ u2out,
                           float* __restrict__ qA, float* __restrict__ qB,
                           float* __restrict__ qC, float* __restrict__ qD,
                           float* __restrict__ H, ushort_t* __restrict__ Hb, int N) {
  int wid  = (int)((blockIdx.x * (unsigned)blockDim.x + threadIdx.x) >> 6);
  int lane = threadIdx.x & 63;
  if (wid >= N) return;
  int n = wid;
  int half = lane >> 5, i = lane & 31;
  bool act = i < 25;
  int j = half * 100 + i * 4;
  float4 accIn = {0.f, 0.f, 0.f, 0.f}, accOut = {0.f, 0.f, 0.f, 0.f};
  if (act) {
    ushort4 pb = *(const ushort4*)(PBb + (size_t)n * 200 + j);
    ushort4 pc = *(const ushort4*)(PCb + (size_t)n * 200 + j);
    accIn.x = bf2f(pb.x); accIn.y = bf2f(pb.y); accIn.z = bf2f(pb.z); accIn.w = bf2f(pb.w);
    accOut.x = bf2f(pc.x); accOut.y = bf2f(pc.y); accOut.z = bf2f(pc.z); accOut.w = bf2f(pc.w);
  }
  int sIn = rsIn[n];
  int degIn = rsIn[n + 1] - sIn;
  if (degIn > 0) {
    float d0 = 0.f, d1 = 0.f;
    for (int b = 0; b < degIn; b += 64) {
      int l = b + lane;
      float e0 = 0.f, e1 = 0.f;
      if (l < degIn) { float2 ev = eIc[sIn + l]; e0 = ev.x; e1 = ev.y; }
#pragma unroll
      for (int m = 1; m < 64; m <<= 1) { e0 += __shfl_xor(e0, m, 64); e1 += __shfl_xor(e1, m, 64); }
      d0 += e0; d1 += e1;
    }
    float invd = 1.f / (half ? d1 : d0);
    for (int b = 0; b < degIn; b += 64) {
      int l = b + lane;
      int r_ = 0, t_ = 0;
      float e0 = 0.f, e1 = 0.f;
      if (l < degIn) {
        int2 pt = pinIn[sIn + l];
        r_ = pt.x; t_ = pt.y;
        float2 ev = eIc[sIn + l];
        e0 = ev.x; e1 = ev.y;
      }
      int m2 = min(64, degIn - b);
      for (int jj = 0; jj < m2; ++jj) {
        float a0 = __shfl(e0, jj, 64), a1 = __shfl(e1, jj, 64);
        int re = __shfl(r_, jj, 64), te = __shfl(t_, jj, 64);
        float alpha = (half ? a1 : a0) * invd;
        if (act) {
          ushort4 pa = *(const ushort4*)(PAb + (size_t)re * 200 + j);
          ushort4 p3 = *(const ushort4*)(P3ib + (size_t)te * 200 + j);
          accIn.x += alpha * (bf2f(pa.x) + bf2f(p3.x));
          accIn.y += alpha * (bf2f(pa.y) + bf2f(p3.y));
          accIn.z += alpha * (bf2f(pa.z) + bf2f(p3.z));
          accIn.w += alpha * (bf2f(pa.w) + bf2f(p3.w));
        }
      }
    }
  }
  int sOut = rsOut[n];
  int degOut = rsOut[n + 1] - sOut;
  if (degOut > 0) {
    float d0 = 0.f, d1 = 0.f;
    for (int b = 0; b < degOut; b += 64) {
      int l = b + lane;
      float e0 = 0.f, e1 = 0.f;
      if (l < degOut) { float2 ev = eOc[sOut + l]; e0 = ev.x; e1 = ev.y; }
#pragma unroll
      for (int m = 1; m < 64; m <<= 1) { e0 += __shfl_xor(e0, m, 64); e1 += __shfl_xor(e1, m, 64); }
      d0 += e0; d1 += e1;
    }
    float invd = 1.f / (half ? d1 : d0);
    for (int b = 0; b < degOut; b += 64) {
      int l = b + lane;
      int c_ = 0, t_ = 0;
      float e0 = 0.f, e1 = 0.f;
      if (l < degOut) {
        int2 pt = pinOut[sOut + l];
        c_ = pt.x; t_ = pt.y;
        float2 ev = eOc[sOut + l];
        e0 = ev.x; e1 = ev.y;
      }
      int m2 = min(64, degOut - b);
      for (int jj = 0; jj < m2; ++jj) {
        float a0 = __shfl(e0, jj, 64), a1 = __shfl(e1, jj, 64);
        int ce = __shfl(c_, jj, 64), te = __shfl(t_, jj, 64);
        float alpha = (half ? a1 : a0) * invd;
        if (act) {
          ushort4 pd = *(const ushort4*)(PDb + (size_t)ce * 200 + j);
          ushort4 p3 = *(const ushort4*)(P3ob + (size_t)te * 200 + j);
          accOut.x += alpha * (bf2f(pd.x) + bf2f(p3.x));
          accOut.y += alpha * (bf2f(pd.y) + bf2f(p3.y));
          accOut.z += alpha * (bf2f(pd.z) + bf2f(p3.z));
          accOut.w += alpha * (bf2f(pd.w) + bf2f(p3.w));
        }
      }
    }
  }
  float4 hin, hout;
  hin.x = degIn > 0 ? elu1(accIn.x) : 0.f;
  hin.y = degIn > 0 ? elu1(accIn.y) : 0.f;
  hin.z = degIn > 0 ? elu1(accIn.z) : 0.f;
  hin.w = degIn > 0 ? elu1(accIn.w) : 0.f;
  hout.x = degOut > 0 ? elu1(accOut.x) : 0.f;
  hout.y = degOut > 0 ? elu1(accOut.y) : 0.f;
  hout.z = degOut > 0 ? elu1(accOut.z) : 0.f;
  hout.w = degOut > 0 ? elu1(accOut.w) : 0.f;
  float gp = 0.f;
  if (act) {
    int k = i * 4;
    gp = Wg[k] * hin.x + Wg[k + 1] * hin.y + Wg[k + 2] * hin.z + Wg[k + 3] * hin.w +
         Wg[100 + k] * hout.x + Wg[100 + k + 1] * hout.y +
         Wg[100 + k + 2] * hout.z + Wg[100 + k + 3] * hout.w;
  }
#pragma unroll
  for (int m = 1; m < 32; m <<= 1) gp += __shfl_xor(gp, m, 32);
  float al = 1.f / (1.f + expf(-(gp + bg[0])));
  float4 he;
  he.x = elu1(al * hin.x + (1.f - al) * hout.x);
  he.y = elu1(al * hin.y + (1.f - al) * hout.y);
  he.z = elu1(al * hin.z + (1.f - al) * hout.z);
  he.w = elu1(al * hin.w + (1.f - al) * hout.w);
  float ss = he.x * he.x + he.y * he.y + he.z * he.z + he.w * he.w;
#pragma unroll
  for (int m = 1; m < 32; m <<= 1) ss += __shfl_xor(ss, m, 32);
  float inv = 1.f / fmaxf(sqrtf(ss), 1e-12f);
  float4 o = {he.x * inv, he.y * inv, he.z * inv, he.w * inv};
  if (act && H) *(float4*)(H + (size_t)n * 200 + j) = o;
  if (Hb) {
    if (act) {
      ushort4 ov; ov.x = f2bf(o.x); ov.y = f2bf(o.y); ov.z = f2bf(o.z); ov.w = f2bf(o.w);
      *(ushort4*)(Hb + (size_t)n * 256 + j) = ov;
    } else {
      int pi = half * 7 + (i - 25);
      ushort4 z = {0, 0, 0, 0};
      *(ushort4*)(Hb + (size_t)n * 256 + 200 + pi * 4) = z;
    }
  }
  // next-layer q dots (layer-1 call only)
  if (u2in) {
    float4 ov = act ? o : make_float4(0.f, 0.f, 0.f, 0.f);
    float s[8];
#pragma unroll
    for (int h = 0; h < 2; ++h) {
      float4 uA = *(const float4*)(u2in + h * 500 + j);
      float4 uB = *(const float4*)(u2in + h * 500 + 200 + j);
      float4 uC = *(const float4*)(u2out + h * 500 + j);
      float4 uD = *(const float4*)(u2out + h * 500 + 200 + j);
      s[0 + h] = ov.x * uA.x + ov.y * uA.y + ov.z * uA.z + ov.w * uA.w;
      s[2 + h] = ov.x * uB.x + ov.y * uB.y + ov.z * uB.z + ov.w * uB.w;
      s[4 + h] = ov.x * uC.x + ov.y * uC.y + ov.z * uC.z + ov.w * uC.w;
      s[6 + h] = ov.x * uD.x + ov.y * uD.y + ov.z * uD.z + ov.w * uD.w;
    }
#pragma unroll
    for (int m = 1; m < 64; m <<= 1) {
#pragma unroll
      for (int ii = 0; ii < 8; ++ii) s[ii] += __shfl_xor(s[ii], m, 64);
    }
    if (lane == 0) {
      qA[n * 2] = s[0]; qA[n * 2 + 1] = s[1];
      qB[n * 2] = s[2]; qB[n * 2 + 1] = s[3];
      qC[n * 2] = s[4]; qC[n * 2 + 1] = s[5];
      qD[n * 2] = s[6]; qD[n * 2 + 1] = s[7];
    }
  }
}

// ---------------- final: out = l2_perhead(hent + h2) ----------------
__global__ void k_final_norm(const float* __restrict__ hent, const float* __restrict__ h2,
                             float* __restrict__ out, int N) {
  int wid  = (int)((blockIdx.x * (unsigned)blockDim.x + threadIdx.x) >> 6);
  int lane = threadIdx.x & 63;
  if (wid >= N) return;
  int n = wid;
  int half = lane >> 5, i = lane & 31;
  bool act = i < 25;
  int j = half * 100 + i * 4;
  float4 v = {0.f, 0.f, 0.f, 0.f};
  if (act) {
    float4 a = *(const float4*)(hent + (size_t)n * 200 + j);
    float4 b = *(const float4*)(h2 + (size_t)n * 200 + j);
    v.x = a.x + b.x; v.y = a.y + b.y; v.z = a.z + b.z; v.w = a.w + b.w;
  }
  float ss = v.x * v.x + v.y * v.y + v.z * v.z + v.w * v.w;
#pragma unroll
  for (int m = 1; m < 32; m <<= 1) ss += __shfl_xor(ss, m, 32);
  float inv = 1.f / fmaxf(sqrtf(ss), 1e-12f);
  if (act) {
    float4 o; o.x = v.x * inv; o.y = v.y * inv; o.z = v.z * inv; o.w = v.w * inv;
    *(float4*)(out + (size_t)n * 200 + j) = o;
  }
}

extern "C" void kernel_launch(void* const* d_in, const int* in_sizes, int n_in,
                              void* d_out, int out_size, void* d_ws, size_t ws_size,
                              hipStream_t stream) {
  const float* x    = (const float*)d_in[0];
  const float* g    = (const float*)d_in[1];
  const float* W1in = (const float*)d_in[2];
  const float* b1in = (const float*)d_in[3];
  const float* a1in = (const float*)d_in[4];
  const float* W1out= (const float*)d_in[5];
  const float* b1out= (const float*)d_in[6];
  const float* a1out= (const float*)d_in[7];
  const float* Wa1  = (const float*)d_in[8];
  const float* ba1  = (const float*)d_in[9];
  const float* W2in = (const float*)d_in[10];
  const float* b2in = (const float*)d_in[11];
  const float* a2in = (const float*)d_in[12];
  const float* W2out= (const float*)d_in[13];
  const float* b2out= (const float*)d_in[14];
  const float* a2out= (const float*)d_in[15];
  const float* Wa2  = (const float*)d_in[16];
  const float* ba2  = (const float*)d_in[17];
  const float* Went = (const float*)d_in[18];
  const float* bent = (const float*)d_in[19];
  const float* Wrel = (const float*)d_in[20];
  const float* brel = (const float*)d_in[21];
  const int*  eidx  = (const int*)d_in[22];
  const int*  ety   = (const int*)d_in[23];

  const int N = in_sizes[0] / 100;
  const int M = in_sizes[1] / 100;
  const int E = in_sizes[23];
  const int* row = eidx;
  const int* col = eidx + E;
  float* out = (float*)d_out;

  float* ws = (float*)d_ws;
  size_t off = 0;
  auto alloc = [&](size_t nf) { float* p = ws + off; off += (nf + 3) & ~(size_t)3; return p; };
  ushort_t* PAb = (ushort_t*)alloc((size_t)N * 100);
  ushort_t* PBb = (ushort_t*)alloc((size_t)N * 100);
  ushort_t* PCb = (ushort_t*)alloc((size_t)N * 100);
  ushort_t* PDb = (ushort_t*)alloc((size_t)N * 100);
  ushort_t* P3ib = (ushort_t*)alloc((size_t)M * 100);
  ushort_t* P3ob = (ushort_t*)alloc((size_t)M * 100);
  ushort_t* xnb = (ushort_t*)alloc((size_t)N * 64);
  ushort_t* h1b = (ushort_t*)alloc((size_t)N * 128);
  ushort_t* wcat1 = (ushort_t*)alloc((size_t)832 * 64);
  ushort_t* wcat2 = (ushort_t*)alloc((size_t)832 * 128);
  ushort_t* wentb = (ushort_t*)alloc((size_t)256 * 64);
  float* qA  = alloc((size_t)N * 2);
  float* qB  = alloc((size_t)N * 2);
  float* qC  = alloc((size_t)N * 2);
  float* qD  = alloc((size_t)N * 2);
  float* q3i1 = alloc((size_t)M * 2);
  float* q3o1 = alloc((size_t)M * 2);
  float* q3i2 = alloc((size_t)M * 2);
  float* q3o2 = alloc((size_t)M * 2);
  float2* eIc = (float2*)alloc((size_t)E * 2);
  float2* eOc = (float2*)alloc((size_t)E * 2);
  int2* pinIn  = (int2*)alloc((size_t)E * 2);
  int2* pinOut = (int2*)alloc((size_t)E * 2);
  int* invIn  = (int*)alloc((size_t)E);
  int* invOut = (int*)alloc((size_t)E);
  float* h2   = alloc((size_t)N * 200);
  float* hent = alloc((size_t)N * 200);
  float* u1in  = alloc(600);
  float* u1out = alloc(600);
  float* u2in  = alloc(1000);
  float* u2out = alloc(1000);
  int* cntIn  = (int*)alloc((size_t)N);
  int* cntOut = (int*)alloc((size_t)N);
  int* rsIn   = (int*)alloc((size_t)N + 1);
  int* rsOut  = (int*)alloc((size_t)N + 1);
  int* posIn  = (int*)alloc((size_t)N);
  int* posOut = (int*)alloc((size_t)N);

  dim3 gm(4, (M + 31) / 32);
  int gN4 = (N + 3) / 4;
  int gE  = (E + 255) / 256;
  int mT = (N + 63) / 64;
  dim3 gq8(13, mT);   // NC=800
  dim3 gq2(4, mT);    // NC=200 (Went)

  // ---------- CSR + precompute ----------
  hipMemsetAsync(cntIn, 0, sizeof(int) * (size_t)N, stream);
  hipMemsetAsync(cntOut, 0, sizeof(int) * (size_t)N, stream);
  k_count<<<gE, 256, 0, stream>>>(row, col, cntIn, cntOut, E);
  k_scan2<<<1, 1024, 0, stream>>>(cntIn, rsIn, posIn, cntOut, rsOut, posOut, N);
  k_fill<<<gE, 256, 0, stream>>>(row, col, ety, posIn, posOut, pinIn, pinOut, invIn, invOut, E);

  k_build_w<<<1376, 256, 0, stream>>>(W1in, W1out, W2in, W2out, Went, wcat1, wcat2, wentb);
  k_makeu_all<<<13, 256, 0, stream>>>(W1in, a1in, W1out, a1out, W2in, a2in, W2out, a2out,
                                      u1in, u1out, u2in, u2out);
  k_l2norm_q<<<gN4, 256, 0, stream>>>(x, xnb, u1in, u1out, qA, qB, qC, qD, N);
  k_qrel2<<<(2 * M + 3) / 4, 256, 0, stream>>>(g, u1in, u1out, u2in, u2out,
                                               q3i1, q3o1, q3i2, q3o2, M);

  // ---------- layer 1 ----------
  k_edge_e<<<gE, 256, 0, stream>>>(row, col, ety, qA, qB, q3i1, qC, qD, q3o1,
                                   invIn, invOut, eIc, eOc, E);
  k_mfma_gemm<<<gq8, 256, 0, stream>>>(xnb, 128, wcat1, 128, N, 800, 200, nullptr,
                                       nullptr, PAb, PBb, PCb, PDb);
  k_gemm_multi<2, 1><<<gm, 256, 0, stream>>>(g, 100, W1in + 200, W1out + 200, 300,
                                             b1in, b1out, P3ib, P3ob, M, 100);
  k_node_att<<<gN4, 256, 0, stream>>>(pinIn, eIc, rsIn, pinOut, eOc, rsOut,
                                      PAb, PBb, PCb, PDb, P3ib, P3ob, Wa1, ba1,
                                      u2in, u2out, qA, qB, qC, qD,
                                      nullptr, h1b, N);

  // ---------- layer 2 ----------
  k_edge_e<<<gE, 256, 0, stream>>>(row, col, ety, qA, qB, q3i2, qC, qD, q3o2,
                                   invIn, invOut, eIc, eOc, E);
  k_mfma_gemm<<<gq8, 256, 0, stream>>>(h1b, 256, wcat2, 256, N, 800, 200, nullptr,
                                       nullptr, PAb, PBb, PCb, PDb);
  k_gemm_multi<2, 1><<<gm, 256, 0, stream>>>(g, 100, W2in + 400, W2out + 400, 500,
                                             b2in, b2out, P3ib, P3ob, M, 100);
  k_node_att<<<gN4, 256, 0, stream>>>(pinIn, eIc, rsIn, pinOut, eOc, rsOut,
                                      PAb, PBb, PCb, PDb, P3ib, P3ob, Wa2, ba2,
                                      nullptr, nullptr, qA, qB, qC, qD,
                                      h2, nullptr, N);

  // ---------- final ----------
  k_mfma_gemm<<<gq2, 256, 0, stream>>>(xnb, 128, wentb, 128, N, 200, 200, bent,
                                       hent, nullptr, nullptr, nullptr, nullptr);
  k_final_norm<<<gN4, 256, 0, stream>>>(hent, h2, out, N);
  k_gemm_multi<1, 0><<<gm, 256, 0, stream>>>(g, 100, Wrel, nullptr, 100,
                                             brel, nullptr, out + (size_t)N * 200, nullptr, M, 100);
}